// Round 13
// baseline (299.974 us; speedup 1.0000x reference)
//
#include <hip/hip_runtime.h>

using u16 = unsigned short;
using u32 = unsigned int;

// Problem constants (from reference)
constexpr int Nn  = 50000;   // nodes
constexpr int Ee  = 800000;  // edges
constexpr int Bb  = 256;     // graphs
constexpr int INF = 32;      // input feature dim
constexpr int Hh  = 96;      // hidden dim
constexpr float BN_EPS = 1e-5f;

// Binned CSR build parameters
constexpr int BINW = 256;                      // nodes per bin
constexpr int NBIN = (Nn + BINW - 1) / BINW;   // 196
constexpr int P1B  = 256;                      // pass-1 blocks
constexpr int EPB  = Ee / P1B;                 // 3125 edges per block (exact)
constexpr int CAP  = 64;                       // per (block,bin) capacity (mean 16, 12 sigma)

// bf16 weight table offsets (u16 units), k-pair-interleaved layout:
//   u32 word i = { lo: w[2*k2][j], hi: w[2*k2+1][j] },  i = base/2 + k2*96 + j
constexpr int W1I_OFF = 0;        // 32*96  = 3072
constexpr int W1O_OFF = 3072;     // 96*96  = 9216
constexpr int W2I_OFF = 12288;
constexpr int W2O_OFF = 21504;
constexpr int W3I_OFF = 30720;
constexpr int W3O_OFF = 39936;
constexpr int WB_TOT  = 49152;    // u16 total

// ---------------- bf16 helpers (rne) ----------------
__device__ __forceinline__ float bfL(u32 u) { return __uint_as_float(u << 16); }
__device__ __forceinline__ float bfH(u32 u) { return __uint_as_float(u & 0xFFFF0000u); }
__device__ __forceinline__ u32 f2bfb(float f) {            // rounded bf16 bits (low 16)
    u32 b = __float_as_uint(f);
    return (b + 0x7FFFu + ((b >> 16) & 1u)) >> 16;
}
__device__ __forceinline__ float bf2f(u16 u) { return __uint_as_float(((u32)u) << 16); }

// ---------------------------------------------------------------------------
// x -> bf16 table (N x 32)
// ---------------------------------------------------------------------------
__global__ void x2bf_kernel(const float* __restrict__ x, u16* __restrict__ xb) {
    const int total = Nn * INF / 8;
    for (int i = blockIdx.x * 256 + threadIdx.x; i < total; i += gridDim.x * 256) {
        const float4 a = ((const float4*)x)[2 * i];
        const float4 b = ((const float4*)x)[2 * i + 1];
        uint4 R;
        R.x = f2bfb(a.x) | (f2bfb(a.y) << 16);
        R.y = f2bfb(a.z) | (f2bfb(a.w) << 16);
        R.z = f2bfb(b.x) | (f2bfb(b.y) << 16);
        R.w = f2bfb(b.z) | (f2bfb(b.w) << 16);
        ((uint4*)xb)[i] = R;
    }
}

// ---------------------------------------------------------------------------
// Weights -> bf16, k-pair interleaved. One u32 output per thread.
// ---------------------------------------------------------------------------
__global__ void w2bf_kernel(const float* __restrict__ w1i, const float* __restrict__ w1o,
                            const float* __restrict__ w2i, const float* __restrict__ w2o,
                            const float* __restrict__ w3i, const float* __restrict__ w3o,
                            u16* __restrict__ wb) {
    const int i = blockIdx.x * 256 + threadIdx.x;     // u32 index
    if (i >= WB_TOT / 2) return;
    const float* src; int base;
    if      (i < 1536)  { src = w1i; base = 0;     }
    else if (i < 6144)  { src = w1o; base = 1536;  }
    else if (i < 10752) { src = w2i; base = 6144;  }
    else if (i < 15360) { src = w2o; base = 10752; }
    else if (i < 19968) { src = w3i; base = 15360; }
    else                { src = w3o; base = 19968; }
    const int local = i - base;
    const int k2 = local / 96, j = local % 96;
    ((u32*)wb)[i] = f2bfb(src[(2 * k2) * 96 + j]) | (f2bfb(src[(2 * k2 + 1) * 96 + j]) << 16);
}

// ---------------------------------------------------------------------------
// CSR build pass 1: bin edges into per-(block,bin) private regions.
// ---------------------------------------------------------------------------
__global__ __launch_bounds__(256)
void p1_bin_kernel(const int* __restrict__ src, const int* __restrict__ dst,
                   u32* __restrict__ binbuf, int* __restrict__ counts) {
    __shared__ int cur[NBIN];
    const int b = blockIdx.x, tid = threadIdx.x;
    for (int k = tid; k < NBIN; k += 256) cur[k] = 0;
    __syncthreads();
    const long e0 = (long)b * EPB;
    for (int i = tid; i < EPB; i += 256) {
        const long e = e0 + i;
        const int d = dst[e];
        const int k = d >> 8;
        const int pos = atomicAdd(&cur[k], 1);
        binbuf[((long)b * NBIN + k) * CAP + pos] = ((u32)(d & 255) << 16) | (u32)src[e];
    }
    __syncthreads();
    for (int k = tid; k < NBIN; k += 256) counts[k * P1B + b] = cur[k];
}

// ---------------------------------------------------------------------------
// CSR build pass 2: bin totals -> exclusive prefix (binbase); rowptr[N] = E.
// ---------------------------------------------------------------------------
__global__ void p2_binscan_kernel(const int* __restrict__ counts, int* __restrict__ binbase,
                                  int* __restrict__ rowptr) {
    __shared__ int ps[256];
    const int t = threadIdx.x;
    int tot = 0;
    if (t < NBIN) {
        const int* cp = counts + t * P1B;
        for (int b = 0; b < P1B; ++b) tot += cp[b];
    }
    ps[t] = tot;
    __syncthreads();
    for (int d = 1; d < 256; d <<= 1) {
        int u = (t >= d) ? ps[t - d] : 0;
        __syncthreads();
        if (t >= d) ps[t] += u;
        __syncthreads();
    }
    if (t < NBIN) binbase[t] = ps[t] - tot;   // exclusive prefix
    if (t == 0) rowptr[Nn] = Ee;
}

// ---------------------------------------------------------------------------
// CSR build pass 3: one block per bin -> rowptr slice + sorted u16 csr window.
// ---------------------------------------------------------------------------
__global__ __launch_bounds__(256)
void p3_binsort_kernel(const u32* __restrict__ binbuf, const int* __restrict__ counts,
                       const int* __restrict__ binbase, int* __restrict__ rowptr,
                       u16* __restrict__ csr) {
    __shared__ int cnt[P1B];
    __shared__ int lhist[BINW];
    __shared__ int lpref[BINW];
    const int k = blockIdx.x, tid = threadIdx.x;

    for (int b = tid; b < P1B; b += 256) cnt[b] = counts[k * P1B + b];
    lhist[tid] = 0;
    __syncthreads();

    for (int flat = tid; flat < P1B * CAP; flat += 256) {
        const int b = flat / CAP, i = flat % CAP;
        if (i < cnt[b])
            atomicAdd(&lhist[binbuf[((long)b * NBIN + k) * CAP + i] >> 16], 1);
    }
    __syncthreads();

    const int v = lhist[tid];
    lpref[tid] = v;
    __syncthreads();
    for (int d = 1; d < 256; d <<= 1) {
        int u = (tid >= d) ? lpref[tid - d] : 0;
        __syncthreads();
        if (tid >= d) lpref[tid] += u;
        __syncthreads();
    }
    lpref[tid] -= v;

    const int base = binbase[k];
    const int node = k * BINW + tid;
    if (node < Nn) rowptr[node] = base + lpref[tid];
    lhist[tid] = 0;                         // reuse as cursor
    __syncthreads();

    for (int flat = tid; flat < P1B * CAP; flat += 256) {
        const int b = flat / CAP, i = flat % CAP;
        if (i < cnt[b]) {
            const u32 pv = binbuf[((long)b * NBIN + k) * CAP + i];
            const int dl = pv >> 16;
            const int pos = base + lpref[dl] + atomicAdd(&lhist[dl], 1);
            csr[pos] = (u16)(pv & 0xFFFFu);
        }
    }
}

// ---------------------------------------------------------------------------
// FULL GIN LAYER: agg + FC1 + BN + ReLU + FC2 + ReLU. 16-node tile, 384 thr.
// Phases:
//   stage w_in ; gather (24 thr/node uint2, 4x unroll)  -> sync
//   GEMM1 (K=DIN) + BN + ReLU, z in regs                -> sync
//   z -> xs tile, wb <- w_out                           -> sync
//   GEMM2 (K=96) + bias + ReLU -> global out
// 6 waves/block, LDS ~21.6 KB -> 5 blocks/CU = 30 waves/CU.
// GEMM thread = (nt = tid/48 -> 2 nodes) x (jt = tid%48 -> 2 feats).
// ---------------------------------------------------------------------------
template<int DIN>
__global__ __launch_bounds__(384, 8)
void layer_kernel(const u16* __restrict__ hsrc, const int* __restrict__ rowptr,
                  const u16* __restrict__ csr,
                  const u16* __restrict__ wbg1, const u16* __restrict__ wbg2,
                  const float* __restrict__ b_in,
                  const float* __restrict__ gamma, const float* __restrict__ beta,
                  const float* __restrict__ rmean, const float* __restrict__ rvar,
                  const float* __restrict__ b_out,
                  u16* __restrict__ out) {
    constexpr int TILE = 16;
    constexpr int XSTU = Hh + 2;              // 98, shared by gather/z tiles
    __shared__ u16 wb[Hh * Hh];               // holds w_in then w_out (k-pair)
    __shared__ u16 xs[TILE * XSTU];

    const int tid = threadIdx.x;
    const int nbase = blockIdx.x * TILE;      // Nn = 3125*16 exactly

    // stage w_in
    for (int i = tid; i < DIN * Hh / 8; i += 384)
        ((uint4*)wb)[i] = ((const uint4*)wbg1)[i];

    // ---- gather phase: 24 lanes per node ----
    {
        const int grp = tid / 24, ln = tid % 24;
        const int node = nbase + grp;
        const int e0 = rowptr[node], e1 = rowptr[node + 1];
        if constexpr (DIN == 96) {
            const uint2* h2 = (const uint2*)hsrc;     // row = 24 uint2
            float a0, a1, a2, a3;
            {
                const uint2 U = h2[(long)node * 24 + ln];
                a0 = bfL(U.x); a1 = bfH(U.x); a2 = bfL(U.y); a3 = bfH(U.y);
            }
            int e = e0;
            for (; e + 4 <= e1; e += 4) {
                const long s0 = csr[e], s1 = csr[e + 1], s2 = csr[e + 2], s3 = csr[e + 3];
                const uint2 U0 = h2[s0 * 24 + ln];
                const uint2 U1 = h2[s1 * 24 + ln];
                const uint2 U2 = h2[s2 * 24 + ln];
                const uint2 U3 = h2[s3 * 24 + ln];
                a0 += bfL(U0.x); a1 += bfH(U0.x); a2 += bfL(U0.y); a3 += bfH(U0.y);
                a0 += bfL(U1.x); a1 += bfH(U1.x); a2 += bfL(U1.y); a3 += bfH(U1.y);
                a0 += bfL(U2.x); a1 += bfH(U2.x); a2 += bfL(U2.y); a3 += bfH(U2.y);
                a0 += bfL(U3.x); a1 += bfH(U3.x); a2 += bfL(U3.y); a3 += bfH(U3.y);
            }
            for (; e < e1; ++e) {
                const uint2 U = h2[(long)csr[e] * 24 + ln];
                a0 += bfL(U.x); a1 += bfH(U.x); a2 += bfL(U.y); a3 += bfH(U.y);
            }
            u32* xp = (u32*)&xs[grp * XSTU + ln * 4];
            xp[0] = f2bfb(a0) | (f2bfb(a1) << 16);
            xp[1] = f2bfb(a2) | (f2bfb(a3) << 16);
        } else {                                      // DIN == 32: 16 lanes/node
            if (ln < 16) {
                const u32* h1 = (const u32*)hsrc;     // row = 16 u32
                float a0, a1;
                {
                    const u32 U = h1[(long)node * 16 + ln];
                    a0 = bfL(U); a1 = bfH(U);
                }
                int e = e0;
                for (; e + 4 <= e1; e += 4) {
                    const long s0 = csr[e], s1 = csr[e + 1], s2 = csr[e + 2], s3 = csr[e + 3];
                    const u32 U0 = h1[s0 * 16 + ln];
                    const u32 U1 = h1[s1 * 16 + ln];
                    const u32 U2 = h1[s2 * 16 + ln];
                    const u32 U3 = h1[s3 * 16 + ln];
                    a0 += bfL(U0); a1 += bfH(U0);
                    a0 += bfL(U1); a1 += bfH(U1);
                    a0 += bfL(U2); a1 += bfH(U2);
                    a0 += bfL(U3); a1 += bfH(U3);
                }
                for (; e < e1; ++e) {
                    const u32 U = h1[(long)csr[e] * 16 + ln];
                    a0 += bfL(U); a1 += bfH(U);
                }
                *(u32*)&xs[grp * XSTU + ln * 2] = f2bfb(a0) | (f2bfb(a1) << 16);
            }
        }
    }

    // thread tiling for both GEMMs: jt -> 2 feats, nt -> 2 nodes
    const int jt = tid % 48, nt = tid / 48;   // nt in [0,8)
    const int j0 = jt * 2;

    // BN constants (GEMM1 epilogue)
    float A0, A1, C0, C1;
    {
        const float s0 = gamma[j0] * rsqrtf(rvar[j0] + BN_EPS);
        const float s1 = gamma[j0 + 1] * rsqrtf(rvar[j0 + 1] + BN_EPS);
        A0 = s0; C0 = (b_in[j0] - rmean[j0]) * s0 + beta[j0];
        A1 = s1; C1 = (b_in[j0 + 1] - rmean[j0 + 1]) * s1 + beta[j0 + 1];
    }
    __syncthreads();

    // ---- GEMM1 (K = DIN) ----
    float acc[2][2] = {};
    #pragma unroll 4
    for (int k2 = 0; k2 < DIN / 2; ++k2) {
        float xlo[2], xhi[2];
        #pragma unroll
        for (int ni = 0; ni < 2; ++ni) {
            const u32 xv = *(const u32*)&xs[(nt * 2 + ni) * XSTU + 2 * k2];
            xlo[ni] = bfL(xv); xhi[ni] = bfH(xv);
        }
        const uint2 wv = *(const uint2*)&((const u32*)wb)[k2 * 96 + j0];
        const float wlo0 = bfL(wv.x), whi0 = bfH(wv.x);
        const float wlo1 = bfL(wv.y), whi1 = bfH(wv.y);
        #pragma unroll
        for (int ni = 0; ni < 2; ++ni) {
            acc[ni][0] = fmaf(xlo[ni], wlo0, acc[ni][0]);
            acc[ni][0] = fmaf(xhi[ni], whi0, acc[ni][0]);
            acc[ni][1] = fmaf(xlo[ni], wlo1, acc[ni][1]);
            acc[ni][1] = fmaf(xhi[ni], whi1, acc[ni][1]);
        }
    }

    // z = relu(BN(acc)) -> bf16 pairs (kept in regs)
    u32 zp[2];
    #pragma unroll
    for (int ni = 0; ni < 2; ++ni) {
        const float r0 = fmaxf(fmaf(acc[ni][0], A0, C0), 0.0f);
        const float r1 = fmaxf(fmaf(acc[ni][1], A1, C1), 0.0f);
        zp[ni] = f2bfb(r0) | (f2bfb(r1) << 16);
    }
    const float B0 = b_out[j0], B1 = b_out[j0 + 1];
    __syncthreads();                          // all GEMM1 reads of xs/wb done

    // z -> xs, wb <- w_out
    #pragma unroll
    for (int ni = 0; ni < 2; ++ni)
        *(u32*)&xs[(nt * 2 + ni) * XSTU + j0] = zp[ni];
    for (int i = tid; i < Hh * Hh / 8; i += 384)
        ((uint4*)wb)[i] = ((const uint4*)wbg2)[i];
    __syncthreads();

    // ---- GEMM2 (K = 96) ----
    float acc2[2][2] = {};
    #pragma unroll 4
    for (int k2 = 0; k2 < Hh / 2; ++k2) {
        float xlo[2], xhi[2];
        #pragma unroll
        for (int ni = 0; ni < 2; ++ni) {
            const u32 xv = *(const u32*)&xs[(nt * 2 + ni) * XSTU + 2 * k2];
            xlo[ni] = bfL(xv); xhi[ni] = bfH(xv);
        }
        const uint2 wv = *(const uint2*)&((const u32*)wb)[k2 * 96 + j0];
        const float wlo0 = bfL(wv.x), whi0 = bfH(wv.x);
        const float wlo1 = bfL(wv.y), whi1 = bfH(wv.y);
        #pragma unroll
        for (int ni = 0; ni < 2; ++ni) {
            acc2[ni][0] = fmaf(xlo[ni], wlo0, acc2[ni][0]);
            acc2[ni][0] = fmaf(xhi[ni], whi0, acc2[ni][0]);
            acc2[ni][1] = fmaf(xlo[ni], wlo1, acc2[ni][1]);
            acc2[ni][1] = fmaf(xhi[ni], whi1, acc2[ni][1]);
        }
    }

    #pragma unroll
    for (int ni = 0; ni < 2; ++ni) {
        const int node = nbase + nt * 2 + ni;
        const float r0 = fmaxf(acc2[ni][0] + B0, 0.0f);
        const float r1 = fmaxf(acc2[ni][1] + B1, 0.0f);
        *(u32*)(out + (long)node * Hh + j0) = f2bfb(r0) | (f2bfb(r1) << 16);
    }
}

// ---------------------------------------------------------------------------
// Chunked pooling over bf16 table (batch sorted; boundary-flush atomics)
// ---------------------------------------------------------------------------
constexpr int PCHUNK = 64;
__global__ void pool_kernel(const u16* __restrict__ h, const int* __restrict__ batch,
                            float* __restrict__ pooled) {
    const int j = threadIdx.x;                 // 0..95
    const int c0 = blockIdx.x * PCHUNK;
    const int c1 = min(c0 + PCHUNK, Nn);
    if (c0 >= Nn) return;

    int bcur = batch[c0];
    float acc = 0.0f;
    for (int n = c0; n < c1; ++n) {
        const int bb = batch[n];
        if (bb != bcur) {
            atomicAdd(&pooled[(long)bcur * Hh + j], acc);
            acc = 0.0f;
            bcur = bb;
        }
        acc += bf2f(h[(long)n * Hh + j]);
    }
    atomicAdd(&pooled[(long)bcur * Hh + j], acc);
}

// ---------------------------------------------------------------------------
// Head: out[b] = dot(pooled[b], head_w[rt[b]]) + head_b[rt[b]]
// ---------------------------------------------------------------------------
__global__ void head_kernel(const float* __restrict__ pooled, const int* __restrict__ rt,
                            const float* __restrict__ hw, const float* __restrict__ hb,
                            float* __restrict__ outv) {
    const int b = blockIdx.x;
    const int lane = threadIdx.x;
    const int t = rt[b];
    const float* pp = pooled + (long)b * Hh;
    const float* wp = hw + (long)t * Hh;
    float s = 0.0f;
    for (int j = lane; j < Hh; j += 64) s += pp[j] * wp[j];
    #pragma unroll
    for (int off = 32; off > 0; off >>= 1) s += __shfl_down(s, off, 64);
    if (lane == 0) outv[b] = s + hb[t];
}

// ---------------------------------------------------------------------------
extern "C" void kernel_launch(void* const* d_in, const int* in_sizes, int n_in,
                              void* d_out, int out_size, void* d_ws, size_t ws_size,
                              hipStream_t stream) {
    const float* x     = (const float*)d_in[0];
    const int*   ei    = (const int*)d_in[1];      // [2, E] flattened int32
    const int*   src   = ei;
    const int*   dst   = ei + Ee;
    const int*   batch = (const int*)d_in[2];
    const int*   rt    = (const int*)d_in[3];

    const float* P[3][8];
    for (int l = 0; l < 3; ++l)
        for (int p = 0; p < 8; ++p)
            P[l][p] = (const float*)d_in[4 + l * 8 + p];
    const float* head_w = (const float*)d_in[28];
    const float* head_b = (const float*)d_in[29];

    // Workspace layout
    const size_t NH = (size_t)Nn * Hh;
    u16*   tA      = (u16*)d_ws;                       // N*H bf16
    u16*   tB      = tA + NH;                          // N*H bf16
    u16*   xb      = tB + NH;                          // N*INF bf16
    u16*   wball   = xb + (size_t)Nn * INF;            // WB_TOT u16
    float* pooled  = (float*)(wball + WB_TOT);         // B*H fp32
    int*   rowptr  = (int*)(pooled + (size_t)Bb * Hh); // N+1 ints
    int*   counts  = rowptr + Nn + 1;                  // NBIN*P1B ints
    int*   binbase = counts + NBIN * P1B;              // NBIN ints
    u16*   csr     = (u16*)(binbase + NBIN);           // E u16
    // binbuf (12.8 MB) overlays tA+tB (19.2 MB) — both dead during CSR build
    u32*   binbuf  = (u32*)tA;
    float* out     = (float*)d_out;

    const dim3 blk256(256), blk384(384), blk96(96);
    const int GRID_L    = Nn / 16;                     // 3125 (exact)
    const int GRID_POOL = (Nn + PCHUNK - 1) / PCHUNK;

    // ----- precompute tables ; build CSR -----
    x2bf_kernel<<<782, blk256, 0, stream>>>(x, xb);
    w2bf_kernel<<<(WB_TOT / 2 + 255) / 256, blk256, 0, stream>>>(
        P[0][0], P[0][6], P[1][0], P[1][6], P[2][0], P[2][6], wball);
    p1_bin_kernel<<<P1B, blk256, 0, stream>>>(src, dst, binbuf, counts);
    p2_binscan_kernel<<<1, blk256, 0, stream>>>(counts, binbase, rowptr);
    p3_binsort_kernel<<<NBIN, blk256, 0, stream>>>(binbuf, counts, binbase, rowptr, csr);

    // ----- Layer 1: xb -> tA -----
    layer_kernel<INF><<<GRID_L, blk384, 0, stream>>>(xb, rowptr, csr,
        wball + W1I_OFF, wball + W1O_OFF,
        P[0][1], P[0][2], P[0][3], P[0][4], P[0][5], P[0][7], tA);

    // ----- Layer 2: tA -> tB -----
    layer_kernel<Hh><<<GRID_L, blk384, 0, stream>>>(tA, rowptr, csr,
        wball + W2I_OFF, wball + W2O_OFF,
        P[1][1], P[1][2], P[1][3], P[1][4], P[1][5], P[1][7], tB);

    // ----- Layer 3: tB -> tA -----
    layer_kernel<Hh><<<GRID_L, blk384, 0, stream>>>(tB, rowptr, csr,
        wball + W3I_OFF, wball + W3O_OFF,
        P[2][1], P[2][2], P[2][3], P[2][4], P[2][5], P[2][7], tA);

    // ----- Pool (chunked) + head -----
    hipMemsetAsync(pooled, 0, (size_t)Bb * Hh * sizeof(float), stream);
    pool_kernel<<<GRID_POOL, blk96, 0, stream>>>(tA, batch, pooled);
    head_kernel<<<Bb, 64, 0, stream>>>(pooled, rt, head_w, head_b, out);
}

// Round 14
// 269.443 us; speedup vs baseline: 1.1133x; 1.1133x over previous
//
#include <hip/hip_runtime.h>

using u16 = unsigned short;
using u32 = unsigned int;

// Problem constants (from reference)
constexpr int Nn  = 50000;   // nodes
constexpr int Ee  = 800000;  // edges
constexpr int Bb  = 256;     // graphs
constexpr int INF = 32;      // input feature dim
constexpr int Hh  = 96;      // hidden dim
constexpr float BN_EPS = 1e-5f;

// Binned CSR build parameters
constexpr int BINW = 256;                      // nodes per bin
constexpr int NBIN = (Nn + BINW - 1) / BINW;   // 196
constexpr int P1B  = 256;                      // pass-1 blocks
constexpr int EPB  = Ee / P1B;                 // 3125 edges per block (exact)
constexpr int CAP  = 64;                       // per (block,bin) capacity (mean 16, 12 sigma)

// bf16 weight table offsets (u16 units), k-pair-interleaved layout:
//   u32 word i = { lo: w[2*k2][j], hi: w[2*k2+1][j] },  i = base/2 + k2*96 + j
constexpr int W1I_OFF = 0;        // 32*96  = 3072
constexpr int W1O_OFF = 3072;     // 96*96  = 9216
constexpr int W2I_OFF = 12288;
constexpr int W2O_OFF = 21504;
constexpr int W3I_OFF = 30720;
constexpr int W3O_OFF = 39936;
constexpr int WB_TOT  = 49152;    // u16 total

// ---------------- bf16 helpers (rne) ----------------
__device__ __forceinline__ float bfL(u32 u) { return __uint_as_float(u << 16); }
__device__ __forceinline__ float bfH(u32 u) { return __uint_as_float(u & 0xFFFF0000u); }
__device__ __forceinline__ u32 f2bfb(float f) {            // rounded bf16 bits (low 16)
    u32 b = __float_as_uint(f);
    return (b + 0x7FFFu + ((b >> 16) & 1u)) >> 16;
}
__device__ __forceinline__ float bf2f(u16 u) { return __uint_as_float(((u32)u) << 16); }

// ---------------------------------------------------------------------------
// x -> bf16 table (N x 32)
// ---------------------------------------------------------------------------
__global__ void x2bf_kernel(const float* __restrict__ x, u16* __restrict__ xb) {
    const int total = Nn * INF / 8;
    for (int i = blockIdx.x * 256 + threadIdx.x; i < total; i += gridDim.x * 256) {
        const float4 a = ((const float4*)x)[2 * i];
        const float4 b = ((const float4*)x)[2 * i + 1];
        uint4 R;
        R.x = f2bfb(a.x) | (f2bfb(a.y) << 16);
        R.y = f2bfb(a.z) | (f2bfb(a.w) << 16);
        R.z = f2bfb(b.x) | (f2bfb(b.y) << 16);
        R.w = f2bfb(b.z) | (f2bfb(b.w) << 16);
        ((uint4*)xb)[i] = R;
    }
}

// ---------------------------------------------------------------------------
// Weights -> bf16, k-pair interleaved. One u32 output per thread.
// ---------------------------------------------------------------------------
__global__ void w2bf_kernel(const float* __restrict__ w1i, const float* __restrict__ w1o,
                            const float* __restrict__ w2i, const float* __restrict__ w2o,
                            const float* __restrict__ w3i, const float* __restrict__ w3o,
                            u16* __restrict__ wb) {
    const int i = blockIdx.x * 256 + threadIdx.x;     // u32 index
    if (i >= WB_TOT / 2) return;
    const float* src; int base;
    if      (i < 1536)  { src = w1i; base = 0;     }
    else if (i < 6144)  { src = w1o; base = 1536;  }
    else if (i < 10752) { src = w2i; base = 6144;  }
    else if (i < 15360) { src = w2o; base = 10752; }
    else if (i < 19968) { src = w3i; base = 15360; }
    else                { src = w3o; base = 19968; }
    const int local = i - base;
    const int k2 = local / 96, j = local % 96;
    ((u32*)wb)[i] = f2bfb(src[(2 * k2) * 96 + j]) | (f2bfb(src[(2 * k2 + 1) * 96 + j]) << 16);
}

// ---------------------------------------------------------------------------
// CSR build pass 1: bin edges into per-(block,bin) private regions.
// ---------------------------------------------------------------------------
__global__ __launch_bounds__(256)
void p1_bin_kernel(const int* __restrict__ src, const int* __restrict__ dst,
                   u32* __restrict__ binbuf, int* __restrict__ counts) {
    __shared__ int cur[NBIN];
    const int b = blockIdx.x, tid = threadIdx.x;
    for (int k = tid; k < NBIN; k += 256) cur[k] = 0;
    __syncthreads();
    const long e0 = (long)b * EPB;
    for (int i = tid; i < EPB; i += 256) {
        const long e = e0 + i;
        const int d = dst[e];
        const int k = d >> 8;
        const int pos = atomicAdd(&cur[k], 1);
        binbuf[((long)b * NBIN + k) * CAP + pos] = ((u32)(d & 255) << 16) | (u32)src[e];
    }
    __syncthreads();
    for (int k = tid; k < NBIN; k += 256) counts[k * P1B + b] = cur[k];
}

// ---------------------------------------------------------------------------
// CSR build pass 2: bin totals -> exclusive prefix (binbase); rowptr[N] = E.
// ---------------------------------------------------------------------------
__global__ void p2_binscan_kernel(const int* __restrict__ counts, int* __restrict__ binbase,
                                  int* __restrict__ rowptr) {
    __shared__ int ps[256];
    const int t = threadIdx.x;
    int tot = 0;
    if (t < NBIN) {
        const int* cp = counts + t * P1B;
        for (int b = 0; b < P1B; ++b) tot += cp[b];
    }
    ps[t] = tot;
    __syncthreads();
    for (int d = 1; d < 256; d <<= 1) {
        int u = (t >= d) ? ps[t - d] : 0;
        __syncthreads();
        if (t >= d) ps[t] += u;
        __syncthreads();
    }
    if (t < NBIN) binbase[t] = ps[t] - tot;   // exclusive prefix
    if (t == 0) rowptr[Nn] = Ee;
}

// ---------------------------------------------------------------------------
// CSR build pass 3: one block per bin -> rowptr slice + sorted u16 csr window.
// ---------------------------------------------------------------------------
__global__ __launch_bounds__(256)
void p3_binsort_kernel(const u32* __restrict__ binbuf, const int* __restrict__ counts,
                       const int* __restrict__ binbase, int* __restrict__ rowptr,
                       u16* __restrict__ csr) {
    __shared__ int cnt[P1B];
    __shared__ int lhist[BINW];
    __shared__ int lpref[BINW];
    const int k = blockIdx.x, tid = threadIdx.x;

    for (int b = tid; b < P1B; b += 256) cnt[b] = counts[k * P1B + b];
    lhist[tid] = 0;
    __syncthreads();

    for (int flat = tid; flat < P1B * CAP; flat += 256) {
        const int b = flat / CAP, i = flat % CAP;
        if (i < cnt[b])
            atomicAdd(&lhist[binbuf[((long)b * NBIN + k) * CAP + i] >> 16], 1);
    }
    __syncthreads();

    const int v = lhist[tid];
    lpref[tid] = v;
    __syncthreads();
    for (int d = 1; d < 256; d <<= 1) {
        int u = (tid >= d) ? lpref[tid - d] : 0;
        __syncthreads();
        if (tid >= d) lpref[tid] += u;
        __syncthreads();
    }
    lpref[tid] -= v;

    const int base = binbase[k];
    const int node = k * BINW + tid;
    if (node < Nn) rowptr[node] = base + lpref[tid];
    lhist[tid] = 0;                         // reuse as cursor
    __syncthreads();

    for (int flat = tid; flat < P1B * CAP; flat += 256) {
        const int b = flat / CAP, i = flat % CAP;
        if (i < cnt[b]) {
            const u32 pv = binbuf[((long)b * NBIN + k) * CAP + i];
            const int dl = pv >> 16;
            const int pos = base + lpref[dl] + atomicAdd(&lhist[dl], 1);
            csr[pos] = (u16)(pv & 0xFFFFu);
        }
    }
}

// ---------------------------------------------------------------------------
// FULL GIN LAYER: agg + FC1 + BN + ReLU + FC2 + ReLU. 32-node tile, 384 thr.
// Gather: 12 thr/node (uint4, 4x unroll) — round-12's proven non-spilling
// code. GEMM: thread = 4 nodes x 2 feats (round-12's proven 48-VGPR layout).
// launch_bounds(384,4): 128-VGPR cap, cannot spill; occupancy comes from
// 6 waves/block x ~5 resident blocks (LDS 24.7 KB) = ~30 waves/CU.
// ---------------------------------------------------------------------------
template<int DIN>
__global__ __launch_bounds__(384, 4)
void layer_kernel(const u16* __restrict__ hsrc, const int* __restrict__ rowptr,
                  const u16* __restrict__ csr,
                  const u16* __restrict__ wbg1, const u16* __restrict__ wbg2,
                  const float* __restrict__ b_in,
                  const float* __restrict__ gamma, const float* __restrict__ beta,
                  const float* __restrict__ rmean, const float* __restrict__ rvar,
                  const float* __restrict__ b_out,
                  u16* __restrict__ out) {
    constexpr int TILE = 32;
    constexpr int XSTU = Hh + 2;              // 98, shared by gather/z tiles
    __shared__ u16 wb[Hh * Hh];               // holds w_in then w_out (k-pair)
    __shared__ u16 xs[TILE * XSTU];

    const int tid = threadIdx.x;
    const int nbase = blockIdx.x * TILE;

    // stage w_in
    for (int i = tid; i < DIN * Hh / 8; i += 384)
        ((uint4*)wb)[i] = ((const uint4*)wbg1)[i];

    // ---- gather phase: 12 lanes per node (uint4 each) ----
    {
        const int grp = tid / 12, ln = tid % 12;
        const int node = nbase + grp;
        if (tid < TILE * 12 && node < Nn) {
            const int e0 = rowptr[node], e1 = rowptr[node + 1];
            if constexpr (DIN == 96) {
                const uint4* h4 = (const uint4*)hsrc;     // row = 12 uint4
                float a0, a1, a2, a3, a4, a5, a6, a7;
                {
                    const uint4 U = h4[(long)node * 12 + ln];
                    a0 = bfL(U.x); a1 = bfH(U.x); a2 = bfL(U.y); a3 = bfH(U.y);
                    a4 = bfL(U.z); a5 = bfH(U.z); a6 = bfL(U.w); a7 = bfH(U.w);
                }
                int e = e0;
                for (; e + 4 <= e1; e += 4) {
                    const long s0 = csr[e], s1 = csr[e + 1], s2 = csr[e + 2], s3 = csr[e + 3];
                    const uint4 U0 = h4[s0 * 12 + ln];
                    const uint4 U1 = h4[s1 * 12 + ln];
                    const uint4 U2 = h4[s2 * 12 + ln];
                    const uint4 U3 = h4[s3 * 12 + ln];
                    a0 += bfL(U0.x); a1 += bfH(U0.x); a2 += bfL(U0.y); a3 += bfH(U0.y);
                    a4 += bfL(U0.z); a5 += bfH(U0.z); a6 += bfL(U0.w); a7 += bfH(U0.w);
                    a0 += bfL(U1.x); a1 += bfH(U1.x); a2 += bfL(U1.y); a3 += bfH(U1.y);
                    a4 += bfL(U1.z); a5 += bfH(U1.z); a6 += bfL(U1.w); a7 += bfH(U1.w);
                    a0 += bfL(U2.x); a1 += bfH(U2.x); a2 += bfL(U2.y); a3 += bfH(U2.y);
                    a4 += bfL(U2.z); a5 += bfH(U2.z); a6 += bfL(U2.w); a7 += bfH(U2.w);
                    a0 += bfL(U3.x); a1 += bfH(U3.x); a2 += bfL(U3.y); a3 += bfH(U3.y);
                    a4 += bfL(U3.z); a5 += bfH(U3.z); a6 += bfL(U3.w); a7 += bfH(U3.w);
                }
                for (; e < e1; ++e) {
                    const uint4 U = h4[(long)csr[e] * 12 + ln];
                    a0 += bfL(U.x); a1 += bfH(U.x); a2 += bfL(U.y); a3 += bfH(U.y);
                    a4 += bfL(U.z); a5 += bfH(U.z); a6 += bfL(U.w); a7 += bfH(U.w);
                }
                u32* xp = (u32*)&xs[grp * XSTU + ln * 8];
                xp[0] = f2bfb(a0) | (f2bfb(a1) << 16);
                xp[1] = f2bfb(a2) | (f2bfb(a3) << 16);
                xp[2] = f2bfb(a4) | (f2bfb(a5) << 16);
                xp[3] = f2bfb(a6) | (f2bfb(a7) << 16);
            } else {                                      // DIN == 32: 8 lanes/node
                if (ln < 8) {
                    const uint2* h2 = (const uint2*)hsrc; // row = 8 uint2
                    float a0, a1, a2, a3;
                    {
                        const uint2 U = h2[(long)node * 8 + ln];
                        a0 = bfL(U.x); a1 = bfH(U.x); a2 = bfL(U.y); a3 = bfH(U.y);
                    }
                    int e = e0;
                    for (; e + 4 <= e1; e += 4) {
                        const long s0 = csr[e], s1 = csr[e + 1], s2 = csr[e + 2], s3 = csr[e + 3];
                        const uint2 U0 = h2[s0 * 8 + ln];
                        const uint2 U1 = h2[s1 * 8 + ln];
                        const uint2 U2 = h2[s2 * 8 + ln];
                        const uint2 U3 = h2[s3 * 8 + ln];
                        a0 += bfL(U0.x); a1 += bfH(U0.x); a2 += bfL(U0.y); a3 += bfH(U0.y);
                        a0 += bfL(U1.x); a1 += bfH(U1.x); a2 += bfL(U1.y); a3 += bfH(U1.y);
                        a0 += bfL(U2.x); a1 += bfH(U2.x); a2 += bfL(U2.y); a3 += bfH(U2.y);
                        a0 += bfL(U3.x); a1 += bfH(U3.x); a2 += bfL(U3.y); a3 += bfH(U3.y);
                    }
                    for (; e < e1; ++e) {
                        const uint2 U = h2[(long)csr[e] * 8 + ln];
                        a0 += bfL(U.x); a1 += bfH(U.x); a2 += bfL(U.y); a3 += bfH(U.y);
                    }
                    u32* xp = (u32*)&xs[grp * XSTU + ln * 4];
                    xp[0] = f2bfb(a0) | (f2bfb(a1) << 16);
                    xp[1] = f2bfb(a2) | (f2bfb(a3) << 16);
                }
            }
        } else if (tid < TILE * 12) {
            // zero-fill rows past Nn so GEMM reads defined data
            u32* xp = (u32*)&xs[grp * XSTU + ln * 8];
            if constexpr (DIN == 96) { xp[0] = xp[1] = xp[2] = xp[3] = 0u; }
            else if (ln < 8) { u32* q = (u32*)&xs[grp * XSTU + ln * 4]; q[0] = q[1] = 0u; }
        }
    }

    // thread tiling for both GEMMs: jt -> 2 feats, nt -> 4 nodes (nt in [0,8))
    const int jt = tid % 48, nt = tid / 48;
    const int j0 = jt * 2;

    // BN constants (GEMM1 epilogue)
    float A0, A1, C0, C1;
    {
        const float s0 = gamma[j0] * rsqrtf(rvar[j0] + BN_EPS);
        const float s1 = gamma[j0 + 1] * rsqrtf(rvar[j0 + 1] + BN_EPS);
        A0 = s0; C0 = (b_in[j0] - rmean[j0]) * s0 + beta[j0];
        A1 = s1; C1 = (b_in[j0 + 1] - rmean[j0 + 1]) * s1 + beta[j0 + 1];
    }
    __syncthreads();

    // ---- GEMM1 (K = DIN) ----
    float acc[4][2] = {};
    #pragma unroll 4
    for (int k2 = 0; k2 < DIN / 2; ++k2) {
        float xlo[4], xhi[4];
        #pragma unroll
        for (int ni = 0; ni < 4; ++ni) {
            const u32 xv = *(const u32*)&xs[(nt * 4 + ni) * XSTU + 2 * k2];
            xlo[ni] = bfL(xv); xhi[ni] = bfH(xv);
        }
        const uint2 wv = *(const uint2*)&((const u32*)wb)[k2 * 96 + j0];
        const float wlo0 = bfL(wv.x), whi0 = bfH(wv.x);
        const float wlo1 = bfL(wv.y), whi1 = bfH(wv.y);
        #pragma unroll
        for (int ni = 0; ni < 4; ++ni) {
            acc[ni][0] = fmaf(xlo[ni], wlo0, acc[ni][0]);
            acc[ni][0] = fmaf(xhi[ni], whi0, acc[ni][0]);
            acc[ni][1] = fmaf(xlo[ni], wlo1, acc[ni][1]);
            acc[ni][1] = fmaf(xhi[ni], whi1, acc[ni][1]);
        }
    }

    // z = relu(BN(acc)) -> bf16 pairs (kept in regs)
    u32 zp[4];
    #pragma unroll
    for (int ni = 0; ni < 4; ++ni) {
        const float r0 = fmaxf(fmaf(acc[ni][0], A0, C0), 0.0f);
        const float r1 = fmaxf(fmaf(acc[ni][1], A1, C1), 0.0f);
        zp[ni] = f2bfb(r0) | (f2bfb(r1) << 16);
    }
    const float B0 = b_out[j0], B1 = b_out[j0 + 1];
    __syncthreads();                          // all GEMM1 reads of xs/wb done

    // z -> xs, wb <- w_out
    #pragma unroll
    for (int ni = 0; ni < 4; ++ni)
        *(u32*)&xs[(nt * 4 + ni) * XSTU + j0] = zp[ni];
    for (int i = tid; i < Hh * Hh / 8; i += 384)
        ((uint4*)wb)[i] = ((const uint4*)wbg2)[i];
    __syncthreads();

    // ---- GEMM2 (K = 96) ----
    float acc2[4][2] = {};
    #pragma unroll 4
    for (int k2 = 0; k2 < Hh / 2; ++k2) {
        float xlo[4], xhi[4];
        #pragma unroll
        for (int ni = 0; ni < 4; ++ni) {
            const u32 xv = *(const u32*)&xs[(nt * 4 + ni) * XSTU + 2 * k2];
            xlo[ni] = bfL(xv); xhi[ni] = bfH(xv);
        }
        const uint2 wv = *(const uint2*)&((const u32*)wb)[k2 * 96 + j0];
        const float wlo0 = bfL(wv.x), whi0 = bfH(wv.x);
        const float wlo1 = bfL(wv.y), whi1 = bfH(wv.y);
        #pragma unroll
        for (int ni = 0; ni < 4; ++ni) {
            acc2[ni][0] = fmaf(xlo[ni], wlo0, acc2[ni][0]);
            acc2[ni][0] = fmaf(xhi[ni], whi0, acc2[ni][0]);
            acc2[ni][1] = fmaf(xlo[ni], wlo1, acc2[ni][1]);
            acc2[ni][1] = fmaf(xhi[ni], whi1, acc2[ni][1]);
        }
    }

    #pragma unroll
    for (int ni = 0; ni < 4; ++ni) {
        const int node = nbase + nt * 4 + ni;
        if (node < Nn) {
            const float r0 = fmaxf(acc2[ni][0] + B0, 0.0f);
            const float r1 = fmaxf(acc2[ni][1] + B1, 0.0f);
            *(u32*)(out + (long)node * Hh + j0) = f2bfb(r0) | (f2bfb(r1) << 16);
        }
    }
}

// ---------------------------------------------------------------------------
// Chunked pooling over bf16 table (batch sorted; boundary-flush atomics)
// ---------------------------------------------------------------------------
constexpr int PCHUNK = 64;
__global__ void pool_kernel(const u16* __restrict__ h, const int* __restrict__ batch,
                            float* __restrict__ pooled) {
    const int j = threadIdx.x;                 // 0..95
    const int c0 = blockIdx.x * PCHUNK;
    const int c1 = min(c0 + PCHUNK, Nn);
    if (c0 >= Nn) return;

    int bcur = batch[c0];
    float acc = 0.0f;
    for (int n = c0; n < c1; ++n) {
        const int bb = batch[n];
        if (bb != bcur) {
            atomicAdd(&pooled[(long)bcur * Hh + j], acc);
            acc = 0.0f;
            bcur = bb;
        }
        acc += bf2f(h[(long)n * Hh + j]);
    }
    atomicAdd(&pooled[(long)bcur * Hh + j], acc);
}

// ---------------------------------------------------------------------------
// Head: out[b] = dot(pooled[b], head_w[rt[b]]) + head_b[rt[b]]
// ---------------------------------------------------------------------------
__global__ void head_kernel(const float* __restrict__ pooled, const int* __restrict__ rt,
                            const float* __restrict__ hw, const float* __restrict__ hb,
                            float* __restrict__ outv) {
    const int b = blockIdx.x;
    const int lane = threadIdx.x;
    const int t = rt[b];
    const float* pp = pooled + (long)b * Hh;
    const float* wp = hw + (long)t * Hh;
    float s = 0.0f;
    for (int j = lane; j < Hh; j += 64) s += pp[j] * wp[j];
    #pragma unroll
    for (int off = 32; off > 0; off >>= 1) s += __shfl_down(s, off, 64);
    if (lane == 0) outv[b] = s + hb[t];
}

// ---------------------------------------------------------------------------
extern "C" void kernel_launch(void* const* d_in, const int* in_sizes, int n_in,
                              void* d_out, int out_size, void* d_ws, size_t ws_size,
                              hipStream_t stream) {
    const float* x     = (const float*)d_in[0];
    const int*   ei    = (const int*)d_in[1];      // [2, E] flattened int32
    const int*   src   = ei;
    const int*   dst   = ei + Ee;
    const int*   batch = (const int*)d_in[2];
    const int*   rt    = (const int*)d_in[3];

    const float* P[3][8];
    for (int l = 0; l < 3; ++l)
        for (int p = 0; p < 8; ++p)
            P[l][p] = (const float*)d_in[4 + l * 8 + p];
    const float* head_w = (const float*)d_in[28];
    const float* head_b = (const float*)d_in[29];

    // Workspace layout
    const size_t NH = (size_t)Nn * Hh;
    u16*   tA      = (u16*)d_ws;                       // N*H bf16
    u16*   tB      = tA + NH;                          // N*H bf16
    u16*   xb      = tB + NH;                          // N*INF bf16
    u16*   wball   = xb + (size_t)Nn * INF;            // WB_TOT u16
    float* pooled  = (float*)(wball + WB_TOT);         // B*H fp32
    int*   rowptr  = (int*)(pooled + (size_t)Bb * Hh); // N+1 ints
    int*   counts  = rowptr + Nn + 1;                  // NBIN*P1B ints
    int*   binbase = counts + NBIN * P1B;              // NBIN ints
    u16*   csr     = (u16*)(binbase + NBIN);           // E u16
    // binbuf (12.8 MB) overlays tA+tB (19.2 MB) — both dead during CSR build
    u32*   binbuf  = (u32*)tA;
    float* out     = (float*)d_out;

    const dim3 blk256(256), blk384(384), blk96(96);
    const int GRID_L    = (Nn + 31) / 32;              // 1563
    const int GRID_POOL = (Nn + PCHUNK - 1) / PCHUNK;

    // ----- precompute tables ; build CSR -----
    x2bf_kernel<<<782, blk256, 0, stream>>>(x, xb);
    w2bf_kernel<<<(WB_TOT / 2 + 255) / 256, blk256, 0, stream>>>(
        P[0][0], P[0][6], P[1][0], P[1][6], P[2][0], P[2][6], wball);
    p1_bin_kernel<<<P1B, blk256, 0, stream>>>(src, dst, binbuf, counts);
    p2_binscan_kernel<<<1, blk256, 0, stream>>>(counts, binbase, rowptr);
    p3_binsort_kernel<<<NBIN, blk256, 0, stream>>>(binbuf, counts, binbase, rowptr, csr);

    // ----- Layer 1: xb -> tA -----
    layer_kernel<INF><<<GRID_L, blk384, 0, stream>>>(xb, rowptr, csr,
        wball + W1I_OFF, wball + W1O_OFF,
        P[0][1], P[0][2], P[0][3], P[0][4], P[0][5], P[0][7], tA);

    // ----- Layer 2: tA -> tB -----
    layer_kernel<Hh><<<GRID_L, blk384, 0, stream>>>(tA, rowptr, csr,
        wball + W2I_OFF, wball + W2O_OFF,
        P[1][1], P[1][2], P[1][3], P[1][4], P[1][5], P[1][7], tB);

    // ----- Layer 3: tB -> tA -----
    layer_kernel<Hh><<<GRID_L, blk384, 0, stream>>>(tB, rowptr, csr,
        wball + W3I_OFF, wball + W3O_OFF,
        P[2][1], P[2][2], P[2][3], P[2][4], P[2][5], P[2][7], tA);

    // ----- Pool (chunked) + head -----
    hipMemsetAsync(pooled, 0, (size_t)Bb * Hh * sizeof(float), stream);
    pool_kernel<<<GRID_POOL, blk96, 0, stream>>>(tA, batch, pooled);
    head_kernel<<<Bb, 64, 0, stream>>>(pooled, rt, head_w, head_b, out);
}

// Round 15
// 179.185 us; speedup vs baseline: 1.6741x; 1.5037x over previous
//
#include <hip/hip_runtime.h>

using u16 = unsigned short;
using u32 = unsigned int;

typedef __attribute__((ext_vector_type(8))) short bf16x8;
typedef __attribute__((ext_vector_type(4))) float f32x4;

// Problem constants (from reference)
constexpr int Nn  = 50000;   // nodes
constexpr int Ee  = 800000;  // edges
constexpr int Bb  = 256;     // graphs
constexpr int INF = 32;      // input feature dim
constexpr int Hh  = 96;      // hidden dim
constexpr float BN_EPS = 1e-5f;

// Binned CSR build parameters
constexpr int BINW = 256;                      // nodes per bin
constexpr int NBIN = (Nn + BINW - 1) / BINW;   // 196
constexpr int P1B  = 256;                      // pass-1 blocks
constexpr int EPB  = Ee / P1B;                 // 3125 edges per block (exact)
constexpr int CAP  = 64;                       // per (block,bin) capacity

// Transposed bf16 weight tables: wT[j][k], k-contiguous, row stride 104 u16.
constexpr int WROW   = 104;                    // k-stride (u16) -> 208B rows, bank-friendly
constexpr int WMAT   = 96 * WROW;              // 9984 u16 per matrix
constexpr int WB_TOT = 6 * WMAT;               // 59904 u16

// ---------------- bf16 helpers (rne) ----------------
__device__ __forceinline__ float bfL(u32 u) { return __uint_as_float(u << 16); }
__device__ __forceinline__ float bfH(u32 u) { return __uint_as_float(u & 0xFFFF0000u); }
__device__ __forceinline__ u32 f2bfb(float f) {            // rounded bf16 bits (low 16)
    u32 b = __float_as_uint(f);
    return (b + 0x7FFFu + ((b >> 16) & 1u)) >> 16;
}
__device__ __forceinline__ float bf2f(u16 u) { return __uint_as_float(((u32)u) << 16); }

// ---------------------------------------------------------------------------
// x -> bf16 table (N x 32)
// ---------------------------------------------------------------------------
__global__ void x2bf_kernel(const float* __restrict__ x, u16* __restrict__ xb) {
    const int total = Nn * INF / 8;
    for (int i = blockIdx.x * 256 + threadIdx.x; i < total; i += gridDim.x * 256) {
        const float4 a = ((const float4*)x)[2 * i];
        const float4 b = ((const float4*)x)[2 * i + 1];
        uint4 R;
        R.x = f2bfb(a.x) | (f2bfb(a.y) << 16);
        R.y = f2bfb(a.z) | (f2bfb(a.w) << 16);
        R.z = f2bfb(b.x) | (f2bfb(b.y) << 16);
        R.w = f2bfb(b.z) | (f2bfb(b.w) << 16);
        ((uint4*)xb)[i] = R;
    }
}

// ---------------------------------------------------------------------------
// Weights -> bf16 TRANSPOSED: wT[j][k] = w[k][j], row stride WROW, zero-pad.
// One u32 (k-pair) per thread.
// ---------------------------------------------------------------------------
__global__ void w2bf_kernel(const float* __restrict__ w1i, const float* __restrict__ w1o,
                            const float* __restrict__ w2i, const float* __restrict__ w2o,
                            const float* __restrict__ w3i, const float* __restrict__ w3o,
                            u16* __restrict__ wb) {
    const int i = blockIdx.x * 256 + threadIdx.x;   // u32 word index
    if (i >= WB_TOT / 2) return;
    const int mat = i / (WMAT / 2);
    const int rem = i % (WMAT / 2);
    const int j   = rem / (WROW / 2);
    const int k   = (rem % (WROW / 2)) * 2;
    const float* src; int din;
    switch (mat) {
        case 0: src = w1i; din = 32; break;
        case 1: src = w1o; din = 96; break;
        case 2: src = w2i; din = 96; break;
        case 3: src = w2o; din = 96; break;
        case 4: src = w3i; din = 96; break;
        default: src = w3o; din = 96; break;
    }
    const u32 lo = (k     < din) ? f2bfb(src[(long)k * 96 + j])       : 0u;
    const u32 hi = (k + 1 < din) ? f2bfb(src[(long)(k + 1) * 96 + j]) : 0u;
    ((u32*)wb)[i] = lo | (hi << 16);
}

// ---------------------------------------------------------------------------
// CSR build pass 1: bin edges into per-(block,bin) private regions.
// ---------------------------------------------------------------------------
__global__ __launch_bounds__(256)
void p1_bin_kernel(const int* __restrict__ src, const int* __restrict__ dst,
                   u32* __restrict__ binbuf, int* __restrict__ counts) {
    __shared__ int cur[NBIN];
    const int b = blockIdx.x, tid = threadIdx.x;
    for (int k = tid; k < NBIN; k += 256) cur[k] = 0;
    __syncthreads();
    const long e0 = (long)b * EPB;
    for (int i = tid; i < EPB; i += 256) {
        const long e = e0 + i;
        const int d = dst[e];
        const int k = d >> 8;
        const int pos = atomicAdd(&cur[k], 1);
        binbuf[((long)b * NBIN + k) * CAP + pos] = ((u32)(d & 255) << 16) | (u32)src[e];
    }
    __syncthreads();
    for (int k = tid; k < NBIN; k += 256) counts[k * P1B + b] = cur[k];
}

// ---------------------------------------------------------------------------
// CSR build pass 2: bin totals -> exclusive prefix (binbase); rowptr[N] = E.
// ---------------------------------------------------------------------------
__global__ void p2_binscan_kernel(const int* __restrict__ counts, int* __restrict__ binbase,
                                  int* __restrict__ rowptr) {
    __shared__ int ps[256];
    const int t = threadIdx.x;
    int tot = 0;
    if (t < NBIN) {
        const int* cp = counts + t * P1B;
        for (int b = 0; b < P1B; ++b) tot += cp[b];
    }
    ps[t] = tot;
    __syncthreads();
    for (int d = 1; d < 256; d <<= 1) {
        int u = (t >= d) ? ps[t - d] : 0;
        __syncthreads();
        if (t >= d) ps[t] += u;
        __syncthreads();
    }
    if (t < NBIN) binbase[t] = ps[t] - tot;   // exclusive prefix
    if (t == 0) rowptr[Nn] = Ee;
}

// ---------------------------------------------------------------------------
// CSR build pass 3: one block per bin -> rowptr slice + sorted u16 csr window.
// ---------------------------------------------------------------------------
__global__ __launch_bounds__(256)
void p3_binsort_kernel(const u32* __restrict__ binbuf, const int* __restrict__ counts,
                       const int* __restrict__ binbase, int* __restrict__ rowptr,
                       u16* __restrict__ csr) {
    __shared__ int cnt[P1B];
    __shared__ int lhist[BINW];
    __shared__ int lpref[BINW];
    const int k = blockIdx.x, tid = threadIdx.x;

    for (int b = tid; b < P1B; b += 256) cnt[b] = counts[k * P1B + b];
    lhist[tid] = 0;
    __syncthreads();

    for (int flat = tid; flat < P1B * CAP; flat += 256) {
        const int b = flat / CAP, i = flat % CAP;
        if (i < cnt[b])
            atomicAdd(&lhist[binbuf[((long)b * NBIN + k) * CAP + i] >> 16], 1);
    }
    __syncthreads();

    const int v = lhist[tid];
    lpref[tid] = v;
    __syncthreads();
    for (int d = 1; d < 256; d <<= 1) {
        int u = (tid >= d) ? lpref[tid - d] : 0;
        __syncthreads();
        if (tid >= d) lpref[tid] += u;
        __syncthreads();
    }
    lpref[tid] -= v;

    const int base = binbase[k];
    const int node = k * BINW + tid;
    if (node < Nn) rowptr[node] = base + lpref[tid];
    lhist[tid] = 0;                         // reuse as cursor
    __syncthreads();

    for (int flat = tid; flat < P1B * CAP; flat += 256) {
        const int b = flat / CAP, i = flat % CAP;
        if (i < cnt[b]) {
            const u32 pv = binbuf[((long)b * NBIN + k) * CAP + i];
            const int dl = pv >> 16;
            const int pos = base + lpref[dl] + atomicAdd(&lhist[dl], 1);
            csr[pos] = (u16)(pv & 0xFFFFu);
        }
    }
}

// ---------------------------------------------------------------------------
// FULL GIN LAYER with MFMA GEMMs. 32-node tile, 384 threads (6 waves).
//   gather (12 thr/node VALU, proven r12/r14 code)        -> sync
//   GEMM1: mfma_f32_16x16x32_bf16, K=DIN; z in regs       -> sync
//   z -> xs (bf16), wT <- w_out                           -> sync
//   GEMM2: mfma, K=96 -> BN-free bias+ReLU -> global
// Wave w owns feature block j = w*16..w*16+15; m-tiles 0 (rows 0-15) and
// 1 (rows 16-31) -> acc0/acc1. Fragments:
//   A: lane holds xs[m*16 + lane%16][kstep*32 + (lane>>4)*8 .. +7]
//   B: lane holds wT[w*16 + lane%16][same k range]   (wT[j][k] = w[k][j])
//   D: lane holds D[(lane>>4)*4 + r][lane%16]        (m89-verified)
// LDS: wT 19968B + xs 6656B = 26.6 KB.
// ---------------------------------------------------------------------------
template<int DIN>
__global__ __launch_bounds__(384, 4)
void layer_kernel(const u16* __restrict__ hsrc, const int* __restrict__ rowptr,
                  const u16* __restrict__ csr,
                  const u16* __restrict__ wbg1, const u16* __restrict__ wbg2,
                  const float* __restrict__ b_in,
                  const float* __restrict__ gamma, const float* __restrict__ beta,
                  const float* __restrict__ rmean, const float* __restrict__ rvar,
                  const float* __restrict__ b_out,
                  u16* __restrict__ out) {
    constexpr int TILE = 32;
    constexpr int XST  = 104;                 // u16 stride (208B rows)
    __shared__ __align__(16) u16 wT[96 * XST];
    __shared__ __align__(16) u16 xs[TILE * XST];

    const int tid = threadIdx.x;
    const int nbase = blockIdx.x * TILE;

    // stage wT(w_in)
    for (int i = tid; i < 96 * XST / 8; i += 384)
        ((uint4*)wT)[i] = ((const uint4*)wbg1)[i];

    // ---- gather phase: 12 lanes per node (uint4 each) ----
    {
        const int grp = tid / 12, ln = tid % 12;
        const int node = nbase + grp;
        if (node < Nn) {
            const int e0 = rowptr[node], e1 = rowptr[node + 1];
            if constexpr (DIN == 96) {
                const uint4* h4 = (const uint4*)hsrc;     // row = 12 uint4
                float a0, a1, a2, a3, a4, a5, a6, a7;
                {
                    const uint4 U = h4[(long)node * 12 + ln];
                    a0 = bfL(U.x); a1 = bfH(U.x); a2 = bfL(U.y); a3 = bfH(U.y);
                    a4 = bfL(U.z); a5 = bfH(U.z); a6 = bfL(U.w); a7 = bfH(U.w);
                }
                int e = e0;
                for (; e + 4 <= e1; e += 4) {
                    const long s0 = csr[e], s1 = csr[e + 1], s2 = csr[e + 2], s3 = csr[e + 3];
                    const uint4 U0 = h4[s0 * 12 + ln];
                    const uint4 U1 = h4[s1 * 12 + ln];
                    const uint4 U2 = h4[s2 * 12 + ln];
                    const uint4 U3 = h4[s3 * 12 + ln];
                    a0 += bfL(U0.x); a1 += bfH(U0.x); a2 += bfL(U0.y); a3 += bfH(U0.y);
                    a4 += bfL(U0.z); a5 += bfH(U0.z); a6 += bfL(U0.w); a7 += bfH(U0.w);
                    a0 += bfL(U1.x); a1 += bfH(U1.x); a2 += bfL(U1.y); a3 += bfH(U1.y);
                    a4 += bfL(U1.z); a5 += bfH(U1.z); a6 += bfL(U1.w); a7 += bfH(U1.w);
                    a0 += bfL(U2.x); a1 += bfH(U2.x); a2 += bfL(U2.y); a3 += bfH(U2.y);
                    a4 += bfL(U2.z); a5 += bfH(U2.z); a6 += bfL(U2.w); a7 += bfH(U2.w);
                    a0 += bfL(U3.x); a1 += bfH(U3.x); a2 += bfL(U3.y); a3 += bfH(U3.y);
                    a4 += bfL(U3.z); a5 += bfH(U3.z); a6 += bfL(U3.w); a7 += bfH(U3.w);
                }
                for (; e < e1; ++e) {
                    const uint4 U = h4[(long)csr[e] * 12 + ln];
                    a0 += bfL(U.x); a1 += bfH(U.x); a2 += bfL(U.y); a3 += bfH(U.y);
                    a4 += bfL(U.z); a5 += bfH(U.z); a6 += bfL(U.w); a7 += bfH(U.w);
                }
                u32* xp = (u32*)&xs[grp * XST + ln * 8];
                xp[0] = f2bfb(a0) | (f2bfb(a1) << 16);
                xp[1] = f2bfb(a2) | (f2bfb(a3) << 16);
                xp[2] = f2bfb(a4) | (f2bfb(a5) << 16);
                xp[3] = f2bfb(a6) | (f2bfb(a7) << 16);
            } else {                                      // DIN == 32: 8 lanes/node
                if (ln < 8) {
                    const uint2* h2 = (const uint2*)hsrc; // row = 8 uint2
                    float a0, a1, a2, a3;
                    {
                        const uint2 U = h2[(long)node * 8 + ln];
                        a0 = bfL(U.x); a1 = bfH(U.x); a2 = bfL(U.y); a3 = bfH(U.y);
                    }
                    int e = e0;
                    for (; e + 4 <= e1; e += 4) {
                        const long s0 = csr[e], s1 = csr[e + 1], s2 = csr[e + 2], s3 = csr[e + 3];
                        const uint2 U0 = h2[s0 * 8 + ln];
                        const uint2 U1 = h2[s1 * 8 + ln];
                        const uint2 U2 = h2[s2 * 8 + ln];
                        const uint2 U3 = h2[s3 * 8 + ln];
                        a0 += bfL(U0.x); a1 += bfH(U0.x); a2 += bfL(U0.y); a3 += bfH(U0.y);
                        a0 += bfL(U1.x); a1 += bfH(U1.x); a2 += bfL(U1.y); a3 += bfH(U1.y);
                        a0 += bfL(U2.x); a1 += bfH(U2.x); a2 += bfL(U2.y); a3 += bfH(U2.y);
                        a0 += bfL(U3.x); a1 += bfH(U3.x); a2 += bfL(U3.y); a3 += bfH(U3.y);
                    }
                    for (; e < e1; ++e) {
                        const uint2 U = h2[(long)csr[e] * 8 + ln];
                        a0 += bfL(U.x); a1 += bfH(U.x); a2 += bfL(U.y); a3 += bfH(U.y);
                    }
                    u32* xp = (u32*)&xs[grp * XST + ln * 4];
                    xp[0] = f2bfb(a0) | (f2bfb(a1) << 16);
                    xp[1] = f2bfb(a2) | (f2bfb(a3) << 16);
                }
            }
        } else {
            // zero-fill rows past Nn so MFMA reads defined data
            if constexpr (DIN == 96) {
                u32* xp = (u32*)&xs[grp * XST + ln * 8];
                xp[0] = xp[1] = xp[2] = xp[3] = 0u;
            } else if (ln < 8) {
                u32* q = (u32*)&xs[grp * XST + ln * 4];
                q[0] = q[1] = 0u;
            }
        }
    }

    // per-lane MFMA geometry
    const int lane = tid & 63, wave = tid >> 6;   // wave = j-block (0..5)
    const int lr = lane & 15;                     // m/n local index
    const int md = (lane >> 4) * 4;               // D row base
    const int lk = (lane >> 4) * 8;               // k base within 32-step
    const int jg = wave * 16 + lr;                // global feature j

    // BN constants (GEMM1 epilogue) + bias (GEMM2)
    const float sA = gamma[jg] * rsqrtf(rvar[jg] + BN_EPS);
    const float sC = (b_in[jg] - rmean[jg]) * sA + beta[jg];
    const float Bo = b_out[jg];
    __syncthreads();

    // ---- GEMM1 (K = DIN) ----
    f32x4 acc0 = {0.f, 0.f, 0.f, 0.f}, acc1 = {0.f, 0.f, 0.f, 0.f};
    #pragma unroll
    for (int ks = 0; ks < DIN / 32; ++ks) {
        const int k0 = ks * 32 + lk;
        const bf16x8 b  = *(const bf16x8*)&wT[jg * XST + k0];
        const bf16x8 a0 = *(const bf16x8*)&xs[lr * XST + k0];
        const bf16x8 a1 = *(const bf16x8*)&xs[(16 + lr) * XST + k0];
        acc0 = __builtin_amdgcn_mfma_f32_16x16x32_bf16(a0, b, acc0, 0, 0, 0);
        acc1 = __builtin_amdgcn_mfma_f32_16x16x32_bf16(a1, b, acc1, 0, 0, 0);
    }

    // z = relu(BN(acc)) -> bf16 (kept in regs across barrier)
    u16 z0[4], z1[4];
    #pragma unroll
    for (int r = 0; r < 4; ++r) {
        z0[r] = (u16)f2bfb(fmaxf(fmaf(acc0[r], sA, sC), 0.0f));
        z1[r] = (u16)f2bfb(fmaxf(fmaf(acc1[r], sA, sC), 0.0f));
    }
    __syncthreads();                              // all GEMM1 reads of xs/wT done

    // z -> xs (D-layout scatter), wT <- w_out
    #pragma unroll
    for (int r = 0; r < 4; ++r) {
        xs[(md + r) * XST + jg]      = z0[r];
        xs[(16 + md + r) * XST + jg] = z1[r];
    }
    for (int i = tid; i < 96 * XST / 8; i += 384)
        ((uint4*)wT)[i] = ((const uint4*)wbg2)[i];
    __syncthreads();

    // ---- GEMM2 (K = 96) ----
    f32x4 o0 = {0.f, 0.f, 0.f, 0.f}, o1 = {0.f, 0.f, 0.f, 0.f};
    #pragma unroll
    for (int ks = 0; ks < 3; ++ks) {
        const int k0 = ks * 32 + lk;
        const bf16x8 b  = *(const bf16x8*)&wT[jg * XST + k0];
        const bf16x8 a0 = *(const bf16x8*)&xs[lr * XST + k0];
        const bf16x8 a1 = *(const bf16x8*)&xs[(16 + lr) * XST + k0];
        o0 = __builtin_amdgcn_mfma_f32_16x16x32_bf16(a0, b, o0, 0, 0, 0);
        o1 = __builtin_amdgcn_mfma_f32_16x16x32_bf16(a1, b, o1, 0, 0, 0);
    }

    #pragma unroll
    for (int r = 0; r < 4; ++r) {
        const int n0 = nbase + md + r;
        if (n0 < Nn)
            out[(long)n0 * Hh + jg] = (u16)f2bfb(fmaxf(o0[r] + Bo, 0.0f));
        const int n1 = nbase + 16 + md + r;
        if (n1 < Nn)
            out[(long)n1 * Hh + jg] = (u16)f2bfb(fmaxf(o1[r] + Bo, 0.0f));
    }
}

// ---------------------------------------------------------------------------
// Chunked pooling over bf16 table (batch sorted; boundary-flush atomics)
// ---------------------------------------------------------------------------
constexpr int PCHUNK = 64;
__global__ void pool_kernel(const u16* __restrict__ h, const int* __restrict__ batch,
                            float* __restrict__ pooled) {
    const int j = threadIdx.x;                 // 0..95
    const int c0 = blockIdx.x * PCHUNK;
    const int c1 = min(c0 + PCHUNK, Nn);
    if (c0 >= Nn) return;

    int bcur = batch[c0];
    float acc = 0.0f;
    for (int n = c0; n < c1; ++n) {
        const int bb = batch[n];
        if (bb != bcur) {
            atomicAdd(&pooled[(long)bcur * Hh + j], acc);
            acc = 0.0f;
            bcur = bb;
        }
        acc += bf2f(h[(long)n * Hh + j]);
    }
    atomicAdd(&pooled[(long)bcur * Hh + j], acc);
}

// ---------------------------------------------------------------------------
// Head: out[b] = dot(pooled[b], head_w[rt[b]]) + head_b[rt[b]]
// ---------------------------------------------------------------------------
__global__ void head_kernel(const float* __restrict__ pooled, const int* __restrict__ rt,
                            const float* __restrict__ hw, const float* __restrict__ hb,
                            float* __restrict__ outv) {
    const int b = blockIdx.x;
    const int lane = threadIdx.x;
    const int t = rt[b];
    const float* pp = pooled + (long)b * Hh;
    const float* wp = hw + (long)t * Hh;
    float s = 0.0f;
    for (int j = lane; j < Hh; j += 64) s += pp[j] * wp[j];
    #pragma unroll
    for (int off = 32; off > 0; off >>= 1) s += __shfl_down(s, off, 64);
    if (lane == 0) outv[b] = s + hb[t];
}

// ---------------------------------------------------------------------------
extern "C" void kernel_launch(void* const* d_in, const int* in_sizes, int n_in,
                              void* d_out, int out_size, void* d_ws, size_t ws_size,
                              hipStream_t stream) {
    const float* x     = (const float*)d_in[0];
    const int*   ei    = (const int*)d_in[1];      // [2, E] flattened int32
    const int*   src   = ei;
    const int*   dst   = ei + Ee;
    const int*   batch = (const int*)d_in[2];
    const int*   rt    = (const int*)d_in[3];

    const float* P[3][8];
    for (int l = 0; l < 3; ++l)
        for (int p = 0; p < 8; ++p)
            P[l][p] = (const float*)d_in[4 + l * 8 + p];
    const float* head_w = (const float*)d_in[28];
    const float* head_b = (const float*)d_in[29];

    // Workspace layout
    const size_t NH = (size_t)Nn * Hh;
    u16*   tA      = (u16*)d_ws;                       // N*H bf16
    u16*   tB      = tA + NH;                          // N*H bf16
    u16*   xb      = tB + NH;                          // N*INF bf16
    u16*   wball   = xb + (size_t)Nn * INF;            // WB_TOT u16 (transposed tables)
    float* pooled  = (float*)(wball + WB_TOT);         // B*H fp32
    int*   rowptr  = (int*)(pooled + (size_t)Bb * Hh); // N+1 ints
    int*   counts  = rowptr + Nn + 1;                  // NBIN*P1B ints
    int*   binbase = counts + NBIN * P1B;              // NBIN ints
    u16*   csr     = (u16*)(binbase + NBIN);           // E u16
    // binbuf (12.8 MB) overlays tA+tB (19.2 MB) — both dead during CSR build
    u32*   binbuf  = (u32*)tA;
    float* out     = (float*)d_out;

    const dim3 blk256(256), blk384(384), blk96(96);
    const int GRID_L    = (Nn + 31) / 32;              // 1563
    const int GRID_POOL = (Nn + PCHUNK - 1) / PCHUNK;

    // ----- precompute tables ; build CSR -----
    x2bf_kernel<<<782, blk256, 0, stream>>>(x, xb);
    w2bf_kernel<<<(WB_TOT / 2 + 255) / 256, blk256, 0, stream>>>(
        P[0][0], P[0][6], P[1][0], P[1][6], P[2][0], P[2][6], wball);
    p1_bin_kernel<<<P1B, blk256, 0, stream>>>(src, dst, binbuf, counts);
    p2_binscan_kernel<<<1, blk256, 0, stream>>>(counts, binbase, rowptr);
    p3_binsort_kernel<<<NBIN, blk256, 0, stream>>>(binbuf, counts, binbase, rowptr, csr);

    // ----- Layer 1: xb -> tA -----
    layer_kernel<INF><<<GRID_L, blk384, 0, stream>>>(xb, rowptr, csr,
        wball + 0 * WMAT, wball + 1 * WMAT,
        P[0][1], P[0][2], P[0][3], P[0][4], P[0][5], P[0][7], tA);

    // ----- Layer 2: tA -> tB -----
    layer_kernel<Hh><<<GRID_L, blk384, 0, stream>>>(tA, rowptr, csr,
        wball + 2 * WMAT, wball + 3 * WMAT,
        P[1][1], P[1][2], P[1][3], P[1][4], P[1][5], P[1][7], tB);

    // ----- Layer 3: tB -> tA -----
    layer_kernel<Hh><<<GRID_L, blk384, 0, stream>>>(tB, rowptr, csr,
        wball + 4 * WMAT, wball + 5 * WMAT,
        P[2][1], P[2][2], P[2][3], P[2][4], P[2][5], P[2][7], tA);

    // ----- Pool (chunked) + head -----
    hipMemsetAsync(pooled, 0, (size_t)Bb * Hh * sizeof(float), stream);
    pool_kernel<<<GRID_POOL, blk96, 0, stream>>>(tA, batch, pooled);
    head_kernel<<<Bb, 64, 0, stream>>>(pooled, rt, head_w, head_b, out);
}

// Round 16
// 167.390 us; speedup vs baseline: 1.7921x; 1.0705x over previous
//
#include <hip/hip_runtime.h>

using u16 = unsigned short;
using u32 = unsigned int;
using u64 = unsigned long long;

typedef __attribute__((ext_vector_type(8))) short bf16x8;
typedef __attribute__((ext_vector_type(4))) float f32x4;

// Problem constants (from reference)
constexpr int Nn  = 50000;   // nodes
constexpr int Ee  = 800000;  // edges
constexpr int Bb  = 256;     // graphs
constexpr int INF = 32;      // input feature dim
constexpr int Hh  = 96;      // hidden dim
constexpr float BN_EPS = 1e-5f;

// Binned CSR build parameters
constexpr int BINW = 128;                      // nodes per bin
constexpr int NBIN = (Nn + BINW - 1) / BINW;   // 391
constexpr int P1B  = 256;                      // pass-1 blocks
constexpr int EPB  = Ee / P1B;                 // 3125 edges per block (exact)
constexpr int CAP  = 40;                       // per (block,bin) capacity (mean 8, ~8e-15 tail)
constexpr int P3IT = P1B * CAP / 256;          // 40 iterations per p3 thread

// Transposed bf16 weight tables: wT[j][k], k-contiguous, row stride 104 u16.
constexpr int WROW   = 104;                    // k-stride (u16) -> 208B rows, bank-friendly
constexpr int WMAT   = 96 * WROW;              // 9984 u16 per matrix
constexpr int WB_TOT = 6 * WMAT;               // 59904 u16

// ---------------- bf16 helpers (rne) ----------------
__device__ __forceinline__ float bfL(u32 u) { return __uint_as_float(u << 16); }
__device__ __forceinline__ float bfH(u32 u) { return __uint_as_float(u & 0xFFFF0000u); }
__device__ __forceinline__ u32 f2bfb(float f) {            // rounded bf16 bits (low 16)
    u32 b = __float_as_uint(f);
    return (b + 0x7FFFu + ((b >> 16) & 1u)) >> 16;
}
__device__ __forceinline__ float bf2f(u16 u) { return __uint_as_float(((u32)u) << 16); }

// ---------------------------------------------------------------------------
// x -> bf16 table (N x 32)
// ---------------------------------------------------------------------------
__global__ void x2bf_kernel(const float* __restrict__ x, u16* __restrict__ xb) {
    const int total = Nn * INF / 8;
    for (int i = blockIdx.x * 256 + threadIdx.x; i < total; i += gridDim.x * 256) {
        const float4 a = ((const float4*)x)[2 * i];
        const float4 b = ((const float4*)x)[2 * i + 1];
        uint4 R;
        R.x = f2bfb(a.x) | (f2bfb(a.y) << 16);
        R.y = f2bfb(a.z) | (f2bfb(a.w) << 16);
        R.z = f2bfb(b.x) | (f2bfb(b.y) << 16);
        R.w = f2bfb(b.z) | (f2bfb(b.w) << 16);
        ((uint4*)xb)[i] = R;
    }
}

// ---------------------------------------------------------------------------
// Weights -> bf16 TRANSPOSED: wT[j][k] = w[k][j], row stride WROW, zero-pad.
// ---------------------------------------------------------------------------
__global__ void w2bf_kernel(const float* __restrict__ w1i, const float* __restrict__ w1o,
                            const float* __restrict__ w2i, const float* __restrict__ w2o,
                            const float* __restrict__ w3i, const float* __restrict__ w3o,
                            u16* __restrict__ wb) {
    const int i = blockIdx.x * 256 + threadIdx.x;   // u32 word index
    if (i >= WB_TOT / 2) return;
    const int mat = i / (WMAT / 2);
    const int rem = i % (WMAT / 2);
    const int j   = rem / (WROW / 2);
    const int k   = (rem % (WROW / 2)) * 2;
    const float* src; int din;
    switch (mat) {
        case 0: src = w1i; din = 32; break;
        case 1: src = w1o; din = 96; break;
        case 2: src = w2i; din = 96; break;
        case 3: src = w2o; din = 96; break;
        case 4: src = w3i; din = 96; break;
        default: src = w3o; din = 96; break;
    }
    const u32 lo = (k     < din) ? f2bfb(src[(long)k * 96 + j])       : 0u;
    const u32 hi = (k + 1 < din) ? f2bfb(src[(long)(k + 1) * 96 + j]) : 0u;
    ((u32*)wb)[i] = lo | (hi << 16);
}

// ---------------------------------------------------------------------------
// CSR build pass 1: bin edges into per-(block,bin) private regions.
// Also accumulates per-bin totals (bintot) via global atomics for p2.
// ---------------------------------------------------------------------------
__global__ __launch_bounds__(256)
void p1_bin_kernel(const int* __restrict__ src, const int* __restrict__ dst,
                   u32* __restrict__ binbuf, int* __restrict__ counts,
                   int* __restrict__ bintot) {
    __shared__ int cur[NBIN];
    const int b = blockIdx.x, tid = threadIdx.x;
    for (int k = tid; k < NBIN; k += 256) cur[k] = 0;
    __syncthreads();
    const long e0 = (long)b * EPB;
    for (int i = tid; i < EPB; i += 256) {
        const long e = e0 + i;
        const int d = dst[e];
        const int k = d >> 7;                              // BINW = 128
        const int pos = atomicAdd(&cur[k], 1);
        binbuf[((long)b * NBIN + k) * CAP + pos] = ((u32)(d & 127) << 16) | (u32)src[e];
    }
    __syncthreads();
    for (int k = tid; k < NBIN; k += 256) {
        const int c = cur[k];
        counts[k * P1B + b] = c;
        if (c) atomicAdd(&bintot[k], c);
    }
}

// ---------------------------------------------------------------------------
// CSR build pass 2: scan of bintot -> binbase; rowptr[N] = E. 512 threads.
// ---------------------------------------------------------------------------
__global__ void p2_binscan_kernel(const int* __restrict__ bintot, int* __restrict__ binbase,
                                  int* __restrict__ rowptr) {
    __shared__ int ps[512];
    const int t = threadIdx.x;
    const int v = (t < NBIN) ? bintot[t] : 0;
    ps[t] = v;
    __syncthreads();
    for (int d = 1; d < 512; d <<= 1) {
        int u = (t >= d) ? ps[t - d] : 0;
        __syncthreads();
        if (t >= d) ps[t] += u;
        __syncthreads();
    }
    if (t < NBIN) binbase[t] = ps[t] - v;   // exclusive prefix
    if (t == 0) rowptr[Nn] = Ee;
}

// ---------------------------------------------------------------------------
// CSR build pass 3: one block per bin. Payloads register-cached in pass 1
// (no second global read). 391 blocks, 40 unrolled iters/thread.
// ---------------------------------------------------------------------------
__global__ __launch_bounds__(256)
void p3_binsort_kernel(const u32* __restrict__ binbuf, const int* __restrict__ counts,
                       const int* __restrict__ binbase, int* __restrict__ rowptr,
                       u16* __restrict__ csr) {
    __shared__ int cnt[P1B];
    __shared__ int lhist[BINW];
    __shared__ int lpref[BINW];
    const int k = blockIdx.x, tid = threadIdx.x;

    for (int b = tid; b < P1B; b += 256) cnt[b] = counts[k * P1B + b];
    if (tid < BINW) lhist[tid] = 0;
    __syncthreads();

    // pass 1: load + histogram, caching payloads in registers
    u32 pv[P3IT];
    u64 vmask = 0;
    #pragma unroll
    for (int it = 0; it < P3IT; ++it) {
        const int flat = tid + it * 256;
        const int b = flat / CAP, i = flat % CAP;
        if (i < cnt[b]) {
            const u32 v = binbuf[((long)b * NBIN + k) * CAP + i];
            pv[it] = v;
            vmask |= 1ull << it;
            atomicAdd(&lhist[v >> 16], 1);
        }
    }
    __syncthreads();

    // exclusive scan of lhist -> lpref (threads 0..127)
    if (tid < BINW) lpref[tid] = lhist[tid];
    __syncthreads();
    for (int d = 1; d < BINW; d <<= 1) {
        int u = 0;
        if (tid < BINW && tid >= d) u = lpref[tid - d];
        __syncthreads();
        if (tid < BINW && tid >= d) lpref[tid] += u;
        __syncthreads();
    }
    if (tid < BINW) lpref[tid] -= lhist[tid];

    const int base = binbase[k];
    const int node = k * BINW + tid;
    if (tid < BINW && node < Nn) rowptr[node] = base + lpref[tid];
    if (tid < BINW) lhist[tid] = 0;                 // reuse as cursor
    __syncthreads();

    // pass 2: scatter from registers
    #pragma unroll
    for (int it = 0; it < P3IT; ++it) {
        if (vmask & (1ull << it)) {
            const u32 v = pv[it];
            const int dl = v >> 16;
            const int pos = base + lpref[dl] + atomicAdd(&lhist[dl], 1);
            csr[pos] = (u16)(v & 0xFFFFu);
        }
    }
}

// ---------------------------------------------------------------------------
// FULL GIN LAYER with MFMA GEMMs. 32-node tile, 384 threads (6 waves).
// (unchanged from round 15 — verified, 35 us/layer)
// ---------------------------------------------------------------------------
template<int DIN>
__global__ __launch_bounds__(384, 4)
void layer_kernel(const u16* __restrict__ hsrc, const int* __restrict__ rowptr,
                  const u16* __restrict__ csr,
                  const u16* __restrict__ wbg1, const u16* __restrict__ wbg2,
                  const float* __restrict__ b_in,
                  const float* __restrict__ gamma, const float* __restrict__ beta,
                  const float* __restrict__ rmean, const float* __restrict__ rvar,
                  const float* __restrict__ b_out,
                  u16* __restrict__ out) {
    constexpr int TILE = 32;
    constexpr int XST  = 104;                 // u16 stride (208B rows)
    __shared__ __align__(16) u16 wT[96 * XST];
    __shared__ __align__(16) u16 xs[TILE * XST];

    const int tid = threadIdx.x;
    const int nbase = blockIdx.x * TILE;

    // stage wT(w_in)
    for (int i = tid; i < 96 * XST / 8; i += 384)
        ((uint4*)wT)[i] = ((const uint4*)wbg1)[i];

    // ---- gather phase: 12 lanes per node (uint4 each) ----
    {
        const int grp = tid / 12, ln = tid % 12;
        const int node = nbase + grp;
        if (node < Nn) {
            const int e0 = rowptr[node], e1 = rowptr[node + 1];
            if constexpr (DIN == 96) {
                const uint4* h4 = (const uint4*)hsrc;     // row = 12 uint4
                float a0, a1, a2, a3, a4, a5, a6, a7;
                {
                    const uint4 U = h4[(long)node * 12 + ln];
                    a0 = bfL(U.x); a1 = bfH(U.x); a2 = bfL(U.y); a3 = bfH(U.y);
                    a4 = bfL(U.z); a5 = bfH(U.z); a6 = bfL(U.w); a7 = bfH(U.w);
                }
                int e = e0;
                for (; e + 4 <= e1; e += 4) {
                    const long s0 = csr[e], s1 = csr[e + 1], s2 = csr[e + 2], s3 = csr[e + 3];
                    const uint4 U0 = h4[s0 * 12 + ln];
                    const uint4 U1 = h4[s1 * 12 + ln];
                    const uint4 U2 = h4[s2 * 12 + ln];
                    const uint4 U3 = h4[s3 * 12 + ln];
                    a0 += bfL(U0.x); a1 += bfH(U0.x); a2 += bfL(U0.y); a3 += bfH(U0.y);
                    a4 += bfL(U0.z); a5 += bfH(U0.z); a6 += bfL(U0.w); a7 += bfH(U0.w);
                    a0 += bfL(U1.x); a1 += bfH(U1.x); a2 += bfL(U1.y); a3 += bfH(U1.y);
                    a4 += bfL(U1.z); a5 += bfH(U1.z); a6 += bfL(U1.w); a7 += bfH(U1.w);
                    a0 += bfL(U2.x); a1 += bfH(U2.x); a2 += bfL(U2.y); a3 += bfH(U2.y);
                    a4 += bfL(U2.z); a5 += bfH(U2.z); a6 += bfL(U2.w); a7 += bfH(U2.w);
                    a0 += bfL(U3.x); a1 += bfH(U3.x); a2 += bfL(U3.y); a3 += bfH(U3.y);
                    a4 += bfL(U3.z); a5 += bfH(U3.z); a6 += bfL(U3.w); a7 += bfH(U3.w);
                }
                for (; e < e1; ++e) {
                    const uint4 U = h4[(long)csr[e] * 12 + ln];
                    a0 += bfL(U.x); a1 += bfH(U.x); a2 += bfL(U.y); a3 += bfH(U.y);
                    a4 += bfL(U.z); a5 += bfH(U.z); a6 += bfL(U.w); a7 += bfH(U.w);
                }
                u32* xp = (u32*)&xs[grp * XST + ln * 8];
                xp[0] = f2bfb(a0) | (f2bfb(a1) << 16);
                xp[1] = f2bfb(a2) | (f2bfb(a3) << 16);
                xp[2] = f2bfb(a4) | (f2bfb(a5) << 16);
                xp[3] = f2bfb(a6) | (f2bfb(a7) << 16);
            } else {                                      // DIN == 32: 8 lanes/node
                if (ln < 8) {
                    const uint2* h2 = (const uint2*)hsrc; // row = 8 uint2
                    float a0, a1, a2, a3;
                    {
                        const uint2 U = h2[(long)node * 8 + ln];
                        a0 = bfL(U.x); a1 = bfH(U.x); a2 = bfL(U.y); a3 = bfH(U.y);
                    }
                    int e = e0;
                    for (; e + 4 <= e1; e += 4) {
                        const long s0 = csr[e], s1 = csr[e + 1], s2 = csr[e + 2], s3 = csr[e + 3];
                        const uint2 U0 = h2[s0 * 8 + ln];
                        const uint2 U1 = h2[s1 * 8 + ln];
                        const uint2 U2 = h2[s2 * 8 + ln];
                        const uint2 U3 = h2[s3 * 8 + ln];
                        a0 += bfL(U0.x); a1 += bfH(U0.x); a2 += bfL(U0.y); a3 += bfH(U0.y);
                        a0 += bfL(U1.x); a1 += bfH(U1.x); a2 += bfL(U1.y); a3 += bfH(U1.y);
                        a0 += bfL(U2.x); a1 += bfH(U2.x); a2 += bfL(U2.y); a3 += bfH(U2.y);
                        a0 += bfL(U3.x); a1 += bfH(U3.x); a2 += bfL(U3.y); a3 += bfH(U3.y);
                    }
                    for (; e < e1; ++e) {
                        const uint2 U = h2[(long)csr[e] * 8 + ln];
                        a0 += bfL(U.x); a1 += bfH(U.x); a2 += bfL(U.y); a3 += bfH(U.y);
                    }
                    u32* xp = (u32*)&xs[grp * XST + ln * 4];
                    xp[0] = f2bfb(a0) | (f2bfb(a1) << 16);
                    xp[1] = f2bfb(a2) | (f2bfb(a3) << 16);
                }
            }
        } else {
            // zero-fill rows past Nn so MFMA reads defined data
            if constexpr (DIN == 96) {
                u32* xp = (u32*)&xs[grp * XST + ln * 8];
                xp[0] = xp[1] = xp[2] = xp[3] = 0u;
            } else if (ln < 8) {
                u32* q = (u32*)&xs[grp * XST + ln * 4];
                q[0] = q[1] = 0u;
            }
        }
    }

    // per-lane MFMA geometry
    const int lane = tid & 63, wave = tid >> 6;   // wave = j-block (0..5)
    const int lr = lane & 15;                     // m/n local index
    const int md = (lane >> 4) * 4;               // D row base
    const int lk = (lane >> 4) * 8;               // k base within 32-step
    const int jg = wave * 16 + lr;                // global feature j

    // BN constants (GEMM1 epilogue) + bias (GEMM2)
    const float sA = gamma[jg] * rsqrtf(rvar[jg] + BN_EPS);
    const float sC = (b_in[jg] - rmean[jg]) * sA + beta[jg];
    const float Bo = b_out[jg];
    __syncthreads();

    // ---- GEMM1 (K = DIN) ----
    f32x4 acc0 = {0.f, 0.f, 0.f, 0.f}, acc1 = {0.f, 0.f, 0.f, 0.f};
    #pragma unroll
    for (int ks = 0; ks < DIN / 32; ++ks) {
        const int k0 = ks * 32 + lk;
        const bf16x8 b  = *(const bf16x8*)&wT[jg * XST + k0];
        const bf16x8 a0 = *(const bf16x8*)&xs[lr * XST + k0];
        const bf16x8 a1 = *(const bf16x8*)&xs[(16 + lr) * XST + k0];
        acc0 = __builtin_amdgcn_mfma_f32_16x16x32_bf16(a0, b, acc0, 0, 0, 0);
        acc1 = __builtin_amdgcn_mfma_f32_16x16x32_bf16(a1, b, acc1, 0, 0, 0);
    }

    // z = relu(BN(acc)) -> bf16 (kept in regs across barrier)
    u16 z0[4], z1[4];
    #pragma unroll
    for (int r = 0; r < 4; ++r) {
        z0[r] = (u16)f2bfb(fmaxf(fmaf(acc0[r], sA, sC), 0.0f));
        z1[r] = (u16)f2bfb(fmaxf(fmaf(acc1[r], sA, sC), 0.0f));
    }
    __syncthreads();                              // all GEMM1 reads of xs/wT done

    // z -> xs (D-layout scatter), wT <- w_out
    #pragma unroll
    for (int r = 0; r < 4; ++r) {
        xs[(md + r) * XST + jg]      = z0[r];
        xs[(16 + md + r) * XST + jg] = z1[r];
    }
    for (int i = tid; i < 96 * XST / 8; i += 384)
        ((uint4*)wT)[i] = ((const uint4*)wbg2)[i];
    __syncthreads();

    // ---- GEMM2 (K = 96) ----
    f32x4 o0 = {0.f, 0.f, 0.f, 0.f}, o1 = {0.f, 0.f, 0.f, 0.f};
    #pragma unroll
    for (int ks = 0; ks < 3; ++ks) {
        const int k0 = ks * 32 + lk;
        const bf16x8 b  = *(const bf16x8*)&wT[jg * XST + k0];
        const bf16x8 a0 = *(const bf16x8*)&xs[lr * XST + k0];
        const bf16x8 a1 = *(const bf16x8*)&xs[(16 + lr) * XST + k0];
        o0 = __builtin_amdgcn_mfma_f32_16x16x32_bf16(a0, b, o0, 0, 0, 0);
        o1 = __builtin_amdgcn_mfma_f32_16x16x32_bf16(a1, b, o1, 0, 0, 0);
    }

    #pragma unroll
    for (int r = 0; r < 4; ++r) {
        const int n0 = nbase + md + r;
        if (n0 < Nn)
            out[(long)n0 * Hh + jg] = (u16)f2bfb(fmaxf(o0[r] + Bo, 0.0f));
        const int n1 = nbase + 16 + md + r;
        if (n1 < Nn)
            out[(long)n1 * Hh + jg] = (u16)f2bfb(fmaxf(o1[r] + Bo, 0.0f));
    }
}

// ---------------------------------------------------------------------------
// Chunked pooling over bf16 table (batch sorted; boundary-flush atomics)
// ---------------------------------------------------------------------------
constexpr int PCHUNK = 64;
__global__ void pool_kernel(const u16* __restrict__ h, const int* __restrict__ batch,
                            float* __restrict__ pooled) {
    const int j = threadIdx.x;                 // 0..95
    const int c0 = blockIdx.x * PCHUNK;
    const int c1 = min(c0 + PCHUNK, Nn);
    if (c0 >= Nn) return;

    int bcur = batch[c0];
    float acc = 0.0f;
    for (int n = c0; n < c1; ++n) {
        const int bb = batch[n];
        if (bb != bcur) {
            atomicAdd(&pooled[(long)bcur * Hh + j], acc);
            acc = 0.0f;
            bcur = bb;
        }
        acc += bf2f(h[(long)n * Hh + j]);
    }
    atomicAdd(&pooled[(long)bcur * Hh + j], acc);
}

// ---------------------------------------------------------------------------
// Head: out[b] = dot(pooled[b], head_w[rt[b]]) + head_b[rt[b]]
// ---------------------------------------------------------------------------
__global__ void head_kernel(const float* __restrict__ pooled, const int* __restrict__ rt,
                            const float* __restrict__ hw, const float* __restrict__ hb,
                            float* __restrict__ outv) {
    const int b = blockIdx.x;
    const int lane = threadIdx.x;
    const int t = rt[b];
    const float* pp = pooled + (long)b * Hh;
    const float* wp = hw + (long)t * Hh;
    float s = 0.0f;
    for (int j = lane; j < Hh; j += 64) s += pp[j] * wp[j];
    #pragma unroll
    for (int off = 32; off > 0; off >>= 1) s += __shfl_down(s, off, 64);
    if (lane == 0) outv[b] = s + hb[t];
}

// ---------------------------------------------------------------------------
extern "C" void kernel_launch(void* const* d_in, const int* in_sizes, int n_in,
                              void* d_out, int out_size, void* d_ws, size_t ws_size,
                              hipStream_t stream) {
    const float* x     = (const float*)d_in[0];
    const int*   ei    = (const int*)d_in[1];      // [2, E] flattened int32
    const int*   src   = ei;
    const int*   dst   = ei + Ee;
    const int*   batch = (const int*)d_in[2];
    const int*   rt    = (const int*)d_in[3];

    const float* P[3][8];
    for (int l = 0; l < 3; ++l)
        for (int p = 0; p < 8; ++p)
            P[l][p] = (const float*)d_in[4 + l * 8 + p];
    const float* head_w = (const float*)d_in[28];
    const float* head_b = (const float*)d_in[29];

    // Workspace layout
    const size_t NH = (size_t)Nn * Hh;
    u16*   tA      = (u16*)d_ws;                       // N*H bf16
    u16*   tB      = tA + NH;                          // N*H bf16
    u16*   xb      = tB + NH;                          // N*INF bf16
    u16*   wball   = xb + (size_t)Nn * INF;            // WB_TOT u16 (transposed tables)
    float* pooled  = (float*)(wball + WB_TOT);         // B*H fp32
    int*   rowptr  = (int*)(pooled + (size_t)Bb * Hh); // N+1 ints
    int*   counts  = rowptr + Nn + 1;                  // NBIN*P1B ints
    int*   binbase = counts + NBIN * P1B;              // NBIN ints
    int*   bintot  = binbase + NBIN;                   // NBIN ints
    u16*   csr     = (u16*)(bintot + NBIN);            // E u16
    // binbuf (16.0 MB) overlays tA+tB (19.2 MB) — both dead during CSR build
    u32*   binbuf  = (u32*)tA;
    float* out     = (float*)d_out;

    const dim3 blk256(256), blk384(384), blk512(512), blk96(96);
    const int GRID_L    = (Nn + 31) / 32;              // 1563
    const int GRID_POOL = (Nn + PCHUNK - 1) / PCHUNK;

    // ----- precompute tables ; build CSR -----
    x2bf_kernel<<<782, blk256, 0, stream>>>(x, xb);
    w2bf_kernel<<<(WB_TOT / 2 + 255) / 256, blk256, 0, stream>>>(
        P[0][0], P[0][6], P[1][0], P[1][6], P[2][0], P[2][6], wball);
    hipMemsetAsync(bintot, 0, NBIN * sizeof(int), stream);
    p1_bin_kernel<<<P1B, blk256, 0, stream>>>(src, dst, binbuf, counts, bintot);
    p2_binscan_kernel<<<1, blk512, 0, stream>>>(bintot, binbase, rowptr);
    p3_binsort_kernel<<<NBIN, blk256, 0, stream>>>(binbuf, counts, binbase, rowptr, csr);

    // ----- Layer 1: xb -> tA -----
    layer_kernel<INF><<<GRID_L, blk384, 0, stream>>>(xb, rowptr, csr,
        wball + 0 * WMAT, wball + 1 * WMAT,
        P[0][1], P[0][2], P[0][3], P[0][4], P[0][5], P[0][7], tA);

    // ----- Layer 2: tA -> tB -----
    layer_kernel<Hh><<<GRID_L, blk384, 0, stream>>>(tA, rowptr, csr,
        wball + 2 * WMAT, wball + 3 * WMAT,
        P[1][1], P[1][2], P[1][3], P[1][4], P[1][5], P[1][7], tB);

    // ----- Layer 3: tB -> tA -----
    layer_kernel<Hh><<<GRID_L, blk384, 0, stream>>>(tB, rowptr, csr,
        wball + 4 * WMAT, wball + 5 * WMAT,
        P[2][1], P[2][2], P[2][3], P[2][4], P[2][5], P[2][7], tA);

    // ----- Pool (chunked) + head -----
    hipMemsetAsync(pooled, 0, (size_t)Bb * Hh * sizeof(float), stream);
    pool_kernel<<<GRID_POOL, blk96, 0, stream>>>(tA, batch, pooled);
    head_kernel<<<Bb, 64, 0, stream>>>(pooled, rt, head_w, head_b, out);
}

// Round 17
// 152.335 us; speedup vs baseline: 1.9692x; 1.0988x over previous
//
#include <hip/hip_runtime.h>

using u16 = unsigned short;
using u32 = unsigned int;
using u64 = unsigned long long;

typedef __attribute__((ext_vector_type(8))) short bf16x8;
typedef __attribute__((ext_vector_type(4))) float f32x4;

// Problem constants (from reference)
constexpr int Nn  = 50000;   // nodes
constexpr int Ee  = 800000;  // edges
constexpr int Bb  = 256;     // graphs
constexpr int INF = 32;      // input feature dim
constexpr int Hh  = 96;      // hidden dim
constexpr float BN_EPS = 1e-5f;

// Binned CSR build parameters
constexpr int BINW = 128;                      // nodes per bin
constexpr int NBIN = (Nn + BINW - 1) / BINW;   // 391
constexpr int P1B  = 256;                      // pass-1 blocks
constexpr int EPB  = Ee / P1B;                 // 3125 edges per block (exact)
constexpr int CAP  = 40;                       // per (block,bin) capacity (mean 8, ~8e-15 tail)
constexpr int P3IT = P1B * CAP / 256;          // 40 iterations per p3 thread

// Transposed bf16 weight tables: wT[j][k], k-contiguous, row stride 104 u16.
constexpr int WROW   = 104;
constexpr int WMAT   = 96 * WROW;              // 9984 u16 per matrix
constexpr int WB_TOT = 6 * WMAT;               // 59904 u16

// ---------------- bf16 helpers (rne) ----------------
__device__ __forceinline__ float bfL(u32 u) { return __uint_as_float(u << 16); }
__device__ __forceinline__ float bfH(u32 u) { return __uint_as_float(u & 0xFFFF0000u); }
__device__ __forceinline__ u32 f2bfb(float f) {            // rounded bf16 bits (low 16)
    u32 b = __float_as_uint(f);
    return (b + 0x7FFFu + ((b >> 16) & 1u)) >> 16;
}
__device__ __forceinline__ float bf2f(u16 u) { return __uint_as_float(((u32)u) << 16); }

// ---------------------------------------------------------------------------
// x -> bf16 table (N x 32)
// ---------------------------------------------------------------------------
__global__ void x2bf_kernel(const float* __restrict__ x, u16* __restrict__ xb) {
    const int total = Nn * INF / 8;
    for (int i = blockIdx.x * 256 + threadIdx.x; i < total; i += gridDim.x * 256) {
        const float4 a = ((const float4*)x)[2 * i];
        const float4 b = ((const float4*)x)[2 * i + 1];
        uint4 R;
        R.x = f2bfb(a.x) | (f2bfb(a.y) << 16);
        R.y = f2bfb(a.z) | (f2bfb(a.w) << 16);
        R.z = f2bfb(b.x) | (f2bfb(b.y) << 16);
        R.w = f2bfb(b.z) | (f2bfb(b.w) << 16);
        ((uint4*)xb)[i] = R;
    }
}

// ---------------------------------------------------------------------------
// Weights -> bf16 TRANSPOSED: wT[j][k] = w[k][j], row stride WROW, zero-pad.
// ---------------------------------------------------------------------------
__global__ void w2bf_kernel(const float* __restrict__ w1i, const float* __restrict__ w1o,
                            const float* __restrict__ w2i, const float* __restrict__ w2o,
                            const float* __restrict__ w3i, const float* __restrict__ w3o,
                            u16* __restrict__ wb) {
    const int i = blockIdx.x * 256 + threadIdx.x;   // u32 word index
    if (i >= WB_TOT / 2) return;
    const int mat = i / (WMAT / 2);
    const int rem = i % (WMAT / 2);
    const int j   = rem / (WROW / 2);
    const int k   = (rem % (WROW / 2)) * 2;
    const float* src; int din;
    switch (mat) {
        case 0: src = w1i; din = 32; break;
        case 1: src = w1o; din = 96; break;
        case 2: src = w2i; din = 96; break;
        case 3: src = w2o; din = 96; break;
        case 4: src = w3i; din = 96; break;
        default: src = w3o; din = 96; break;
    }
    const u32 lo = (k     < din) ? f2bfb(src[(long)k * 96 + j])       : 0u;
    const u32 hi = (k + 1 < din) ? f2bfb(src[(long)(k + 1) * 96 + j]) : 0u;
    ((u32*)wb)[i] = lo | (hi << 16);
}

// ---------------------------------------------------------------------------
// CSR build pass 1: bin edges into per-(block,bin) private regions.
// ---------------------------------------------------------------------------
__global__ __launch_bounds__(256)
void p1_bin_kernel(const int* __restrict__ src, const int* __restrict__ dst,
                   u32* __restrict__ binbuf, int* __restrict__ counts,
                   int* __restrict__ bintot) {
    __shared__ int cur[NBIN];
    const int b = blockIdx.x, tid = threadIdx.x;
    for (int k = tid; k < NBIN; k += 256) cur[k] = 0;
    __syncthreads();
    const long e0 = (long)b * EPB;
    for (int i = tid; i < EPB; i += 256) {
        const long e = e0 + i;
        const int d = dst[e];
        const int k = d >> 7;                              // BINW = 128
        const int pos = atomicAdd(&cur[k], 1);
        binbuf[((long)b * NBIN + k) * CAP + pos] = ((u32)(d & 127) << 16) | (u32)src[e];
    }
    __syncthreads();
    for (int k = tid; k < NBIN; k += 256) {
        const int c = cur[k];
        counts[k * P1B + b] = c;
        if (c) atomicAdd(&bintot[k], c);
    }
}

// ---------------------------------------------------------------------------
// CSR build pass 2: scan of bintot -> binbase; rowptr[N] = E. 512 threads.
// ---------------------------------------------------------------------------
__global__ void p2_binscan_kernel(const int* __restrict__ bintot, int* __restrict__ binbase,
                                  int* __restrict__ rowptr) {
    __shared__ int ps[512];
    const int t = threadIdx.x;
    const int v = (t < NBIN) ? bintot[t] : 0;
    ps[t] = v;
    __syncthreads();
    for (int d = 1; d < 512; d <<= 1) {
        int u = (t >= d) ? ps[t - d] : 0;
        __syncthreads();
        if (t >= d) ps[t] += u;
        __syncthreads();
    }
    if (t < NBIN) binbase[t] = ps[t] - v;   // exclusive prefix
    if (t == 0) rowptr[Nn] = Ee;
}

// ---------------------------------------------------------------------------
// CSR build pass 3: one block per bin; payloads register-cached.
// ---------------------------------------------------------------------------
__global__ __launch_bounds__(256)
void p3_binsort_kernel(const u32* __restrict__ binbuf, const int* __restrict__ counts,
                       const int* __restrict__ binbase, int* __restrict__ rowptr,
                       u16* __restrict__ csr) {
    __shared__ int cnt[P1B];
    __shared__ int lhist[BINW];
    __shared__ int lpref[BINW];
    const int k = blockIdx.x, tid = threadIdx.x;

    for (int b = tid; b < P1B; b += 256) cnt[b] = counts[k * P1B + b];
    if (tid < BINW) lhist[tid] = 0;
    __syncthreads();

    u32 pv[P3IT];
    u64 vmask = 0;
    #pragma unroll
    for (int it = 0; it < P3IT; ++it) {
        const int flat = tid + it * 256;
        const int b = flat / CAP, i = flat % CAP;
        if (i < cnt[b]) {
            const u32 v = binbuf[((long)b * NBIN + k) * CAP + i];
            pv[it] = v;
            vmask |= 1ull << it;
            atomicAdd(&lhist[v >> 16], 1);
        }
    }
    __syncthreads();

    if (tid < BINW) lpref[tid] = lhist[tid];
    __syncthreads();
    for (int d = 1; d < BINW; d <<= 1) {
        int u = 0;
        if (tid < BINW && tid >= d) u = lpref[tid - d];
        __syncthreads();
        if (tid < BINW && tid >= d) lpref[tid] += u;
        __syncthreads();
    }
    if (tid < BINW) lpref[tid] -= lhist[tid];

    const int base = binbase[k];
    const int node = k * BINW + tid;
    if (tid < BINW && node < Nn) rowptr[node] = base + lpref[tid];
    if (tid < BINW) lhist[tid] = 0;                 // reuse as cursor
    __syncthreads();

    #pragma unroll
    for (int it = 0; it < P3IT; ++it) {
        if (vmask & (1ull << it)) {
            const u32 v = pv[it];
            const int dl = v >> 16;
            const int pos = base + lpref[dl] + atomicAdd(&lhist[dl], 1);
            csr[pos] = (u16)(v & 0xFFFFu);
        }
    }
}

// ---------------------------------------------------------------------------
// FULL GIN LAYER with MFMA GEMMs. 32-node tile, 384 threads (6 waves).
// Gather 8x-unrolled. POOL=true (layer 3): fused graph pooling from the
// epilogue values staged into xs (batch sorted; boundary-flush atomics).
// ---------------------------------------------------------------------------
template<int DIN, bool POOL>
__global__ __launch_bounds__(384, 4)
void layer_kernel(const u16* __restrict__ hsrc, const int* __restrict__ rowptr,
                  const u16* __restrict__ csr,
                  const u16* __restrict__ wbg1, const u16* __restrict__ wbg2,
                  const float* __restrict__ b_in,
                  const float* __restrict__ gamma, const float* __restrict__ beta,
                  const float* __restrict__ rmean, const float* __restrict__ rvar,
                  const float* __restrict__ b_out,
                  u16* __restrict__ out,
                  const int* __restrict__ batch, float* __restrict__ pooled) {
    constexpr int TILE = 32;
    constexpr int XST  = 104;                 // u16 stride (208B rows)
    __shared__ __align__(16) u16 wT[96 * XST];
    __shared__ __align__(16) u16 xs[TILE * XST];

    const int tid = threadIdx.x;
    const int nbase = blockIdx.x * TILE;

    // stage wT(w_in)
    for (int i = tid; i < 96 * XST / 8; i += 384)
        ((uint4*)wT)[i] = ((const uint4*)wbg1)[i];

    // ---- gather phase: 12 lanes per node (uint4 each), 8x edge unroll ----
    {
        const int grp = tid / 12, ln = tid % 12;
        const int node = nbase + grp;
        if (node < Nn) {
            const int e0 = rowptr[node], e1 = rowptr[node + 1];
            if constexpr (DIN == 96) {
                const uint4* h4 = (const uint4*)hsrc;     // row = 12 uint4
                float a0, a1, a2, a3, a4, a5, a6, a7;
                {
                    const uint4 U = h4[(long)node * 12 + ln];
                    a0 = bfL(U.x); a1 = bfH(U.x); a2 = bfL(U.y); a3 = bfH(U.y);
                    a4 = bfL(U.z); a5 = bfH(U.z); a6 = bfL(U.w); a7 = bfH(U.w);
                }
                int e = e0;
                for (; e + 8 <= e1; e += 8) {
                    uint4 U[8];
                    #pragma unroll
                    for (int q = 0; q < 8; ++q) U[q] = h4[(long)csr[e + q] * 12 + ln];
                    #pragma unroll
                    for (int q = 0; q < 8; ++q) {
                        a0 += bfL(U[q].x); a1 += bfH(U[q].x);
                        a2 += bfL(U[q].y); a3 += bfH(U[q].y);
                        a4 += bfL(U[q].z); a5 += bfH(U[q].z);
                        a6 += bfL(U[q].w); a7 += bfH(U[q].w);
                    }
                }
                for (; e + 2 <= e1; e += 2) {
                    const uint4 Ua = h4[(long)csr[e] * 12 + ln];
                    const uint4 Ub = h4[(long)csr[e + 1] * 12 + ln];
                    a0 += bfL(Ua.x); a1 += bfH(Ua.x); a2 += bfL(Ua.y); a3 += bfH(Ua.y);
                    a4 += bfL(Ua.z); a5 += bfH(Ua.z); a6 += bfL(Ua.w); a7 += bfH(Ua.w);
                    a0 += bfL(Ub.x); a1 += bfH(Ub.x); a2 += bfL(Ub.y); a3 += bfH(Ub.y);
                    a4 += bfL(Ub.z); a5 += bfH(Ub.z); a6 += bfL(Ub.w); a7 += bfH(Ub.w);
                }
                if (e < e1) {
                    const uint4 U = h4[(long)csr[e] * 12 + ln];
                    a0 += bfL(U.x); a1 += bfH(U.x); a2 += bfL(U.y); a3 += bfH(U.y);
                    a4 += bfL(U.z); a5 += bfH(U.z); a6 += bfL(U.w); a7 += bfH(U.w);
                }
                u32* xp = (u32*)&xs[grp * XST + ln * 8];
                xp[0] = f2bfb(a0) | (f2bfb(a1) << 16);
                xp[1] = f2bfb(a2) | (f2bfb(a3) << 16);
                xp[2] = f2bfb(a4) | (f2bfb(a5) << 16);
                xp[3] = f2bfb(a6) | (f2bfb(a7) << 16);
            } else {                                      // DIN == 32: 8 lanes/node
                if (ln < 8) {
                    const uint2* h2 = (const uint2*)hsrc; // row = 8 uint2
                    float a0, a1, a2, a3;
                    {
                        const uint2 U = h2[(long)node * 8 + ln];
                        a0 = bfL(U.x); a1 = bfH(U.x); a2 = bfL(U.y); a3 = bfH(U.y);
                    }
                    int e = e0;
                    for (; e + 8 <= e1; e += 8) {
                        uint2 U[8];
                        #pragma unroll
                        for (int q = 0; q < 8; ++q) U[q] = h2[(long)csr[e + q] * 8 + ln];
                        #pragma unroll
                        for (int q = 0; q < 8; ++q) {
                            a0 += bfL(U[q].x); a1 += bfH(U[q].x);
                            a2 += bfL(U[q].y); a3 += bfH(U[q].y);
                        }
                    }
                    for (; e < e1; ++e) {
                        const uint2 U = h2[(long)csr[e] * 8 + ln];
                        a0 += bfL(U.x); a1 += bfH(U.x); a2 += bfL(U.y); a3 += bfH(U.y);
                    }
                    u32* xp = (u32*)&xs[grp * XST + ln * 4];
                    xp[0] = f2bfb(a0) | (f2bfb(a1) << 16);
                    xp[1] = f2bfb(a2) | (f2bfb(a3) << 16);
                }
            }
        } else {
            if constexpr (DIN == 96) {
                u32* xp = (u32*)&xs[grp * XST + ln * 8];
                xp[0] = xp[1] = xp[2] = xp[3] = 0u;
            } else if (ln < 8) {
                u32* q = (u32*)&xs[grp * XST + ln * 4];
                q[0] = q[1] = 0u;
            }
        }
    }

    // per-lane MFMA geometry
    const int lane = tid & 63, wave = tid >> 6;   // wave = j-block (0..5)
    const int lr = lane & 15;                     // m/n local index
    const int md = (lane >> 4) * 4;               // D row base
    const int lk = (lane >> 4) * 8;               // k base within 32-step
    const int jg = wave * 16 + lr;                // global feature j

    const float sA = gamma[jg] * rsqrtf(rvar[jg] + BN_EPS);
    const float sC = (b_in[jg] - rmean[jg]) * sA + beta[jg];
    const float Bo = b_out[jg];
    __syncthreads();

    // ---- GEMM1 (K = DIN) ----
    f32x4 acc0 = {0.f, 0.f, 0.f, 0.f}, acc1 = {0.f, 0.f, 0.f, 0.f};
    #pragma unroll
    for (int ks = 0; ks < DIN / 32; ++ks) {
        const int k0 = ks * 32 + lk;
        const bf16x8 b  = *(const bf16x8*)&wT[jg * XST + k0];
        const bf16x8 a0 = *(const bf16x8*)&xs[lr * XST + k0];
        const bf16x8 a1 = *(const bf16x8*)&xs[(16 + lr) * XST + k0];
        acc0 = __builtin_amdgcn_mfma_f32_16x16x32_bf16(a0, b, acc0, 0, 0, 0);
        acc1 = __builtin_amdgcn_mfma_f32_16x16x32_bf16(a1, b, acc1, 0, 0, 0);
    }

    // z = relu(BN(acc)) -> bf16 (kept in regs across barrier)
    u16 z0[4], z1[4];
    #pragma unroll
    for (int r = 0; r < 4; ++r) {
        z0[r] = (u16)f2bfb(fmaxf(fmaf(acc0[r], sA, sC), 0.0f));
        z1[r] = (u16)f2bfb(fmaxf(fmaf(acc1[r], sA, sC), 0.0f));
    }
    __syncthreads();                              // all GEMM1 reads of xs/wT done

    // z -> xs (D-layout scatter), wT <- w_out
    #pragma unroll
    for (int r = 0; r < 4; ++r) {
        xs[(md + r) * XST + jg]      = z0[r];
        xs[(16 + md + r) * XST + jg] = z1[r];
    }
    for (int i = tid; i < 96 * XST / 8; i += 384)
        ((uint4*)wT)[i] = ((const uint4*)wbg2)[i];
    __syncthreads();

    // ---- GEMM2 (K = 96) ----
    f32x4 o0 = {0.f, 0.f, 0.f, 0.f}, o1 = {0.f, 0.f, 0.f, 0.f};
    #pragma unroll
    for (int ks = 0; ks < 3; ++ks) {
        const int k0 = ks * 32 + lk;
        const bf16x8 b  = *(const bf16x8*)&wT[jg * XST + k0];
        const bf16x8 a0 = *(const bf16x8*)&xs[lr * XST + k0];
        const bf16x8 a1 = *(const bf16x8*)&xs[(16 + lr) * XST + k0];
        o0 = __builtin_amdgcn_mfma_f32_16x16x32_bf16(a0, b, o0, 0, 0, 0);
        o1 = __builtin_amdgcn_mfma_f32_16x16x32_bf16(a1, b, o1, 0, 0, 0);
    }

    u16 y0[4], y1[4];
    #pragma unroll
    for (int r = 0; r < 4; ++r) {
        y0[r] = (u16)f2bfb(fmaxf(o0[r] + Bo, 0.0f));
        y1[r] = (u16)f2bfb(fmaxf(o1[r] + Bo, 0.0f));
    }
    #pragma unroll
    for (int r = 0; r < 4; ++r) {
        const int n0 = nbase + md + r;
        if (n0 < Nn) out[(long)n0 * Hh + jg] = y0[r];
        const int n1 = nbase + 16 + md + r;
        if (n1 < Nn) out[(long)n1 * Hh + jg] = y1[r];
    }

    if constexpr (POOL) {
        __syncthreads();                          // GEMM2 xs reads done
        #pragma unroll
        for (int r = 0; r < 4; ++r) {
            xs[(md + r) * XST + jg]      = y0[r];
            xs[(16 + md + r) * XST + jg] = y1[r];
        }
        __syncthreads();
        if (tid < Hh) {
            const int j = tid;
            float acc = 0.0f;
            int bcur = batch[nbase];
            for (int r = 0; r < TILE; ++r) {
                const int node = nbase + r;
                if (node >= Nn) break;
                const int bb = batch[node];
                if (bb != bcur) {
                    atomicAdd(&pooled[(long)bcur * Hh + j], acc);
                    acc = 0.0f;
                    bcur = bb;
                }
                acc += bf2f(xs[r * XST + j]);
            }
            atomicAdd(&pooled[(long)bcur * Hh + j], acc);
        }
    }
}

// ---------------------------------------------------------------------------
// Head: out[b] = dot(pooled[b], head_w[rt[b]]) + head_b[rt[b]]
// ---------------------------------------------------------------------------
__global__ void head_kernel(const float* __restrict__ pooled, const int* __restrict__ rt,
                            const float* __restrict__ hw, const float* __restrict__ hb,
                            float* __restrict__ outv) {
    const int b = blockIdx.x;
    const int lane = threadIdx.x;
    const int t = rt[b];
    const float* pp = pooled + (long)b * Hh;
    const float* wp = hw + (long)t * Hh;
    float s = 0.0f;
    for (int j = lane; j < Hh; j += 64) s += pp[j] * wp[j];
    #pragma unroll
    for (int off = 32; off > 0; off >>= 1) s += __shfl_down(s, off, 64);
    if (lane == 0) outv[b] = s + hb[t];
}

// ---------------------------------------------------------------------------
extern "C" void kernel_launch(void* const* d_in, const int* in_sizes, int n_in,
                              void* d_out, int out_size, void* d_ws, size_t ws_size,
                              hipStream_t stream) {
    const float* x     = (const float*)d_in[0];
    const int*   ei    = (const int*)d_in[1];      // [2, E] flattened int32
    const int*   src   = ei;
    const int*   dst   = ei + Ee;
    const int*   batch = (const int*)d_in[2];
    const int*   rt    = (const int*)d_in[3];

    const float* P[3][8];
    for (int l = 0; l < 3; ++l)
        for (int p = 0; p < 8; ++p)
            P[l][p] = (const float*)d_in[4 + l * 8 + p];
    const float* head_w = (const float*)d_in[28];
    const float* head_b = (const float*)d_in[29];

    // Workspace layout
    const size_t NH = (size_t)Nn * Hh;
    u16*   tA      = (u16*)d_ws;                       // N*H bf16
    u16*   tB      = tA + NH;                          // N*H bf16
    u16*   xb      = tB + NH;                          // N*INF bf16
    u16*   wball   = xb + (size_t)Nn * INF;            // WB_TOT u16 (transposed tables)
    float* pooled  = (float*)(wball + WB_TOT);         // B*H fp32
    int*   rowptr  = (int*)(pooled + (size_t)Bb * Hh); // N+1 ints
    int*   counts  = rowptr + Nn + 1;                  // NBIN*P1B ints
    int*   binbase = counts + NBIN * P1B;              // NBIN ints
    int*   bintot  = binbase + NBIN;                   // NBIN ints
    u16*   csr     = (u16*)(bintot + NBIN);            // E u16
    // binbuf (16.0 MB) overlays tA+tB (19.2 MB) — both dead during CSR build
    u32*   binbuf  = (u32*)tA;
    float* out     = (float*)d_out;

    const dim3 blk256(256), blk384(384), blk512(512);
    const int GRID_L = (Nn + 31) / 32;                 // 1563

    // ----- precompute tables ; build CSR -----
    x2bf_kernel<<<782, blk256, 0, stream>>>(x, xb);
    w2bf_kernel<<<(WB_TOT / 2 + 255) / 256, blk256, 0, stream>>>(
        P[0][0], P[0][6], P[1][0], P[1][6], P[2][0], P[2][6], wball);
    hipMemsetAsync(bintot, 0, NBIN * sizeof(int), stream);
    p1_bin_kernel<<<P1B, blk256, 0, stream>>>(src, dst, binbuf, counts, bintot);
    p2_binscan_kernel<<<1, blk512, 0, stream>>>(bintot, binbase, rowptr);
    p3_binsort_kernel<<<NBIN, blk256, 0, stream>>>(binbuf, counts, binbase, rowptr, csr);

    // ----- Layer 1: xb -> tA -----
    layer_kernel<INF, false><<<GRID_L, blk384, 0, stream>>>(xb, rowptr, csr,
        wball + 0 * WMAT, wball + 1 * WMAT,
        P[0][1], P[0][2], P[0][3], P[0][4], P[0][5], P[0][7], tA, nullptr, nullptr);

    // ----- Layer 2: tA -> tB -----
    layer_kernel<Hh, false><<<GRID_L, blk384, 0, stream>>>(tA, rowptr, csr,
        wball + 2 * WMAT, wball + 3 * WMAT,
        P[1][1], P[1][2], P[1][3], P[1][4], P[1][5], P[1][7], tB, nullptr, nullptr);

    // ----- Layer 3 (+fused pool): tB -> tA, pooled -----
    hipMemsetAsync(pooled, 0, (size_t)Bb * Hh * sizeof(float), stream);
    layer_kernel<Hh, true><<<GRID_L, blk384, 0, stream>>>(tB, rowptr, csr,
        wball + 4 * WMAT, wball + 5 * WMAT,
        P[2][1], P[2][2], P[2][3], P[2][4], P[2][5], P[2][7], tA, batch, pooled);

    // ----- Head -----
    head_kernel<<<Bb, 64, 0, stream>>>(pooled, rt, head_w, head_b, out);
}

// Round 18
// 146.966 us; speedup vs baseline: 2.0411x; 1.0365x over previous
//
#include <hip/hip_runtime.h>

using u16 = unsigned short;
using u32 = unsigned int;
using u64 = unsigned long long;

typedef __attribute__((ext_vector_type(8))) short bf16x8;
typedef __attribute__((ext_vector_type(4))) float f32x4;

// Problem constants (from reference)
constexpr int Nn  = 50000;   // nodes
constexpr int Ee  = 800000;  // edges
constexpr int Bb  = 256;     // graphs
constexpr int INF = 32;      // input feature dim
constexpr int Hh  = 96;      // hidden dim
constexpr float BN_EPS = 1e-5f;

// Binned CSR build parameters
constexpr int BINW = 128;                      // nodes per bin
constexpr int NBIN = (Nn + BINW - 1) / BINW;   // 391
constexpr int P1B  = 256;                      // pass-1 blocks
constexpr int EPB  = Ee / P1B;                 // 3125 edges per block (exact)
constexpr int CAP  = 40;                       // per (block,bin) capacity (mean 8, ~8e-15 tail)
constexpr int P3IT = P1B * CAP / 256;          // 40 iterations per p3 thread

// Transposed bf16 weight tables: wT[j][k], k-contiguous, row stride 104 u16.
constexpr int WROW   = 104;
constexpr int WMAT   = 96 * WROW;              // 9984 u16 per matrix
constexpr int WB_TOT = 6 * WMAT;               // 59904 u16

// ---------------- bf16 helpers (rne) ----------------
__device__ __forceinline__ float bfL(u32 u) { return __uint_as_float(u << 16); }
__device__ __forceinline__ float bfH(u32 u) { return __uint_as_float(u & 0xFFFF0000u); }
__device__ __forceinline__ u32 f2bfb(float f) {            // rounded bf16 bits (low 16)
    u32 b = __float_as_uint(f);
    return (b + 0x7FFFu + ((b >> 16) & 1u)) >> 16;
}
__device__ __forceinline__ float bf2f(u16 u) { return __uint_as_float(((u32)u) << 16); }

// ---------------------------------------------------------------------------
// x -> bf16 table (N x 32). Also zeroes bintot (391 ints) and pooled
// (Bb*Hh fp32) — replaces two pathologically slow fillBuffer stream nodes.
// ---------------------------------------------------------------------------
__global__ void x2bf_init_kernel(const float* __restrict__ x, u16* __restrict__ xb,
                                 int* __restrict__ bintot, float* __restrict__ pooled) {
    const int gid = blockIdx.x * 256 + threadIdx.x;
    if (gid < NBIN) bintot[gid] = 0;
    if (gid < Bb * Hh) pooled[gid] = 0.0f;

    const int total = Nn * INF / 8;
    for (int i = gid; i < total; i += gridDim.x * 256) {
        const float4 a = ((const float4*)x)[2 * i];
        const float4 b = ((const float4*)x)[2 * i + 1];
        uint4 R;
        R.x = f2bfb(a.x) | (f2bfb(a.y) << 16);
        R.y = f2bfb(a.z) | (f2bfb(a.w) << 16);
        R.z = f2bfb(b.x) | (f2bfb(b.y) << 16);
        R.w = f2bfb(b.z) | (f2bfb(b.w) << 16);
        ((uint4*)xb)[i] = R;
    }
}

// ---------------------------------------------------------------------------
// Weights -> bf16 TRANSPOSED: wT[j][k] = w[k][j], row stride WROW, zero-pad.
// ---------------------------------------------------------------------------
__global__ void w2bf_kernel(const float* __restrict__ w1i, const float* __restrict__ w1o,
                            const float* __restrict__ w2i, const float* __restrict__ w2o,
                            const float* __restrict__ w3i, const float* __restrict__ w3o,
                            u16* __restrict__ wb) {
    const int i = blockIdx.x * 256 + threadIdx.x;   // u32 word index
    if (i >= WB_TOT / 2) return;
    const int mat = i / (WMAT / 2);
    const int rem = i % (WMAT / 2);
    const int j   = rem / (WROW / 2);
    const int k   = (rem % (WROW / 2)) * 2;
    const float* src; int din;
    switch (mat) {
        case 0: src = w1i; din = 32; break;
        case 1: src = w1o; din = 96; break;
        case 2: src = w2i; din = 96; break;
        case 3: src = w2o; din = 96; break;
        case 4: src = w3i; din = 96; break;
        default: src = w3o; din = 96; break;
    }
    const u32 lo = (k     < din) ? f2bfb(src[(long)k * 96 + j])       : 0u;
    const u32 hi = (k + 1 < din) ? f2bfb(src[(long)(k + 1) * 96 + j]) : 0u;
    ((u32*)wb)[i] = lo | (hi << 16);
}

// ---------------------------------------------------------------------------
// CSR build pass 1: bin edges into per-(block,bin) private regions.
// ---------------------------------------------------------------------------
__global__ __launch_bounds__(256)
void p1_bin_kernel(const int* __restrict__ src, const int* __restrict__ dst,
                   u32* __restrict__ binbuf, int* __restrict__ counts,
                   int* __restrict__ bintot) {
    __shared__ int cur[NBIN];
    const int b = blockIdx.x, tid = threadIdx.x;
    for (int k = tid; k < NBIN; k += 256) cur[k] = 0;
    __syncthreads();
    const long e0 = (long)b * EPB;
    for (int i = tid; i < EPB; i += 256) {
        const long e = e0 + i;
        const int d = dst[e];
        const int k = d >> 7;                              // BINW = 128
        const int pos = atomicAdd(&cur[k], 1);
        binbuf[((long)b * NBIN + k) * CAP + pos] = ((u32)(d & 127) << 16) | (u32)src[e];
    }
    __syncthreads();
    for (int k = tid; k < NBIN; k += 256) {
        const int c = cur[k];
        counts[k * P1B + b] = c;
        if (c) atomicAdd(&bintot[k], c);
    }
}

// ---------------------------------------------------------------------------
// CSR build pass 2: scan of bintot -> binbase; rowptr[N] = E. 512 threads.
// ---------------------------------------------------------------------------
__global__ void p2_binscan_kernel(const int* __restrict__ bintot, int* __restrict__ binbase,
                                  int* __restrict__ rowptr) {
    __shared__ int ps[512];
    const int t = threadIdx.x;
    const int v = (t < NBIN) ? bintot[t] : 0;
    ps[t] = v;
    __syncthreads();
    for (int d = 1; d < 512; d <<= 1) {
        int u = (t >= d) ? ps[t - d] : 0;
        __syncthreads();
        if (t >= d) ps[t] += u;
        __syncthreads();
    }
    if (t < NBIN) binbase[t] = ps[t] - v;   // exclusive prefix
    if (t == 0) rowptr[Nn] = Ee;
}

// ---------------------------------------------------------------------------
// CSR build pass 3: one block per bin; payloads register-cached.
// ---------------------------------------------------------------------------
__global__ __launch_bounds__(256)
void p3_binsort_kernel(const u32* __restrict__ binbuf, const int* __restrict__ counts,
                       const int* __restrict__ binbase, int* __restrict__ rowptr,
                       u16* __restrict__ csr) {
    __shared__ int cnt[P1B];
    __shared__ int lhist[BINW];
    __shared__ int lpref[BINW];
    const int k = blockIdx.x, tid = threadIdx.x;

    for (int b = tid; b < P1B; b += 256) cnt[b] = counts[k * P1B + b];
    if (tid < BINW) lhist[tid] = 0;
    __syncthreads();

    u32 pv[P3IT];
    u64 vmask = 0;
    #pragma unroll
    for (int it = 0; it < P3IT; ++it) {
        const int flat = tid + it * 256;
        const int b = flat / CAP, i = flat % CAP;
        if (i < cnt[b]) {
            const u32 v = binbuf[((long)b * NBIN + k) * CAP + i];
            pv[it] = v;
            vmask |= 1ull << it;
            atomicAdd(&lhist[v >> 16], 1);
        }
    }
    __syncthreads();

    if (tid < BINW) lpref[tid] = lhist[tid];
    __syncthreads();
    for (int d = 1; d < BINW; d <<= 1) {
        int u = 0;
        if (tid < BINW && tid >= d) u = lpref[tid - d];
        __syncthreads();
        if (tid < BINW && tid >= d) lpref[tid] += u;
        __syncthreads();
    }
    if (tid < BINW) lpref[tid] -= lhist[tid];

    const int base = binbase[k];
    const int node = k * BINW + tid;
    if (tid < BINW && node < Nn) rowptr[node] = base + lpref[tid];
    if (tid < BINW) lhist[tid] = 0;                 // reuse as cursor
    __syncthreads();

    #pragma unroll
    for (int it = 0; it < P3IT; ++it) {
        if (vmask & (1ull << it)) {
            const u32 v = pv[it];
            const int dl = v >> 16;
            const int pos = base + lpref[dl] + atomicAdd(&lhist[dl], 1);
            csr[pos] = (u16)(v & 0xFFFFu);
        }
    }
}

// ---------------------------------------------------------------------------
// FULL GIN LAYER with MFMA GEMMs. 32-node tile, 384 threads (6 waves).
// Gather 8x-unrolled. POOL=true (layer 3): fused graph pooling.
// ---------------------------------------------------------------------------
template<int DIN, bool POOL>
__global__ __launch_bounds__(384, 4)
void layer_kernel(const u16* __restrict__ hsrc, const int* __restrict__ rowptr,
                  const u16* __restrict__ csr,
                  const u16* __restrict__ wbg1, const u16* __restrict__ wbg2,
                  const float* __restrict__ b_in,
                  const float* __restrict__ gamma, const float* __restrict__ beta,
                  const float* __restrict__ rmean, const float* __restrict__ rvar,
                  const float* __restrict__ b_out,
                  u16* __restrict__ out,
                  const int* __restrict__ batch, float* __restrict__ pooled) {
    constexpr int TILE = 32;
    constexpr int XST  = 104;                 // u16 stride (208B rows)
    __shared__ __align__(16) u16 wT[96 * XST];
    __shared__ __align__(16) u16 xs[TILE * XST];

    const int tid = threadIdx.x;
    const int nbase = blockIdx.x * TILE;

    // stage wT(w_in)
    for (int i = tid; i < 96 * XST / 8; i += 384)
        ((uint4*)wT)[i] = ((const uint4*)wbg1)[i];

    // ---- gather phase: 12 lanes per node (uint4 each), 8x edge unroll ----
    {
        const int grp = tid / 12, ln = tid % 12;
        const int node = nbase + grp;
        if (node < Nn) {
            const int e0 = rowptr[node], e1 = rowptr[node + 1];
            if constexpr (DIN == 96) {
                const uint4* h4 = (const uint4*)hsrc;     // row = 12 uint4
                float a0, a1, a2, a3, a4, a5, a6, a7;
                {
                    const uint4 U = h4[(long)node * 12 + ln];
                    a0 = bfL(U.x); a1 = bfH(U.x); a2 = bfL(U.y); a3 = bfH(U.y);
                    a4 = bfL(U.z); a5 = bfH(U.z); a6 = bfL(U.w); a7 = bfH(U.w);
                }
                int e = e0;
                for (; e + 8 <= e1; e += 8) {
                    uint4 U[8];
                    #pragma unroll
                    for (int q = 0; q < 8; ++q) U[q] = h4[(long)csr[e + q] * 12 + ln];
                    #pragma unroll
                    for (int q = 0; q < 8; ++q) {
                        a0 += bfL(U[q].x); a1 += bfH(U[q].x);
                        a2 += bfL(U[q].y); a3 += bfH(U[q].y);
                        a4 += bfL(U[q].z); a5 += bfH(U[q].z);
                        a6 += bfL(U[q].w); a7 += bfH(U[q].w);
                    }
                }
                for (; e + 2 <= e1; e += 2) {
                    const uint4 Ua = h4[(long)csr[e] * 12 + ln];
                    const uint4 Ub = h4[(long)csr[e + 1] * 12 + ln];
                    a0 += bfL(Ua.x); a1 += bfH(Ua.x); a2 += bfL(Ua.y); a3 += bfH(Ua.y);
                    a4 += bfL(Ua.z); a5 += bfH(Ua.z); a6 += bfL(Ua.w); a7 += bfH(Ua.w);
                    a0 += bfL(Ub.x); a1 += bfH(Ub.x); a2 += bfL(Ub.y); a3 += bfH(Ub.y);
                    a4 += bfL(Ub.z); a5 += bfH(Ub.z); a6 += bfL(Ub.w); a7 += bfH(Ub.w);
                }
                if (e < e1) {
                    const uint4 U = h4[(long)csr[e] * 12 + ln];
                    a0 += bfL(U.x); a1 += bfH(U.x); a2 += bfL(U.y); a3 += bfH(U.y);
                    a4 += bfL(U.z); a5 += bfH(U.z); a6 += bfL(U.w); a7 += bfH(U.w);
                }
                u32* xp = (u32*)&xs[grp * XST + ln * 8];
                xp[0] = f2bfb(a0) | (f2bfb(a1) << 16);
                xp[1] = f2bfb(a2) | (f2bfb(a3) << 16);
                xp[2] = f2bfb(a4) | (f2bfb(a5) << 16);
                xp[3] = f2bfb(a6) | (f2bfb(a7) << 16);
            } else {                                      // DIN == 32: 8 lanes/node
                if (ln < 8) {
                    const uint2* h2 = (const uint2*)hsrc; // row = 8 uint2
                    float a0, a1, a2, a3;
                    {
                        const uint2 U = h2[(long)node * 8 + ln];
                        a0 = bfL(U.x); a1 = bfH(U.x); a2 = bfL(U.y); a3 = bfH(U.y);
                    }
                    int e = e0;
                    for (; e + 8 <= e1; e += 8) {
                        uint2 U[8];
                        #pragma unroll
                        for (int q = 0; q < 8; ++q) U[q] = h2[(long)csr[e + q] * 8 + ln];
                        #pragma unroll
                        for (int q = 0; q < 8; ++q) {
                            a0 += bfL(U[q].x); a1 += bfH(U[q].x);
                            a2 += bfL(U[q].y); a3 += bfH(U[q].y);
                        }
                    }
                    for (; e < e1; ++e) {
                        const uint2 U = h2[(long)csr[e] * 8 + ln];
                        a0 += bfL(U.x); a1 += bfH(U.x); a2 += bfL(U.y); a3 += bfH(U.y);
                    }
                    u32* xp = (u32*)&xs[grp * XST + ln * 4];
                    xp[0] = f2bfb(a0) | (f2bfb(a1) << 16);
                    xp[1] = f2bfb(a2) | (f2bfb(a3) << 16);
                }
            }
        } else {
            if constexpr (DIN == 96) {
                u32* xp = (u32*)&xs[grp * XST + ln * 8];
                xp[0] = xp[1] = xp[2] = xp[3] = 0u;
            } else if (ln < 8) {
                u32* q = (u32*)&xs[grp * XST + ln * 4];
                q[0] = q[1] = 0u;
            }
        }
    }

    // per-lane MFMA geometry
    const int lane = tid & 63, wave = tid >> 6;   // wave = j-block (0..5)
    const int lr = lane & 15;                     // m/n local index
    const int md = (lane >> 4) * 4;               // D row base
    const int lk = (lane >> 4) * 8;               // k base within 32-step
    const int jg = wave * 16 + lr;                // global feature j

    const float sA = gamma[jg] * rsqrtf(rvar[jg] + BN_EPS);
    const float sC = (b_in[jg] - rmean[jg]) * sA + beta[jg];
    const float Bo = b_out[jg];
    __syncthreads();

    // ---- GEMM1 (K = DIN) ----
    f32x4 acc0 = {0.f, 0.f, 0.f, 0.f}, acc1 = {0.f, 0.f, 0.f, 0.f};
    #pragma unroll
    for (int ks = 0; ks < DIN / 32; ++ks) {
        const int k0 = ks * 32 + lk;
        const bf16x8 b  = *(const bf16x8*)&wT[jg * XST + k0];
        const bf16x8 a0 = *(const bf16x8*)&xs[lr * XST + k0];
        const bf16x8 a1 = *(const bf16x8*)&xs[(16 + lr) * XST + k0];
        acc0 = __builtin_amdgcn_mfma_f32_16x16x32_bf16(a0, b, acc0, 0, 0, 0);
        acc1 = __builtin_amdgcn_mfma_f32_16x16x32_bf16(a1, b, acc1, 0, 0, 0);
    }

    // z = relu(BN(acc)) -> bf16 (kept in regs across barrier)
    u16 z0[4], z1[4];
    #pragma unroll
    for (int r = 0; r < 4; ++r) {
        z0[r] = (u16)f2bfb(fmaxf(fmaf(acc0[r], sA, sC), 0.0f));
        z1[r] = (u16)f2bfb(fmaxf(fmaf(acc1[r], sA, sC), 0.0f));
    }
    __syncthreads();                              // all GEMM1 reads of xs/wT done

    // z -> xs (D-layout scatter), wT <- w_out
    #pragma unroll
    for (int r = 0; r < 4; ++r) {
        xs[(md + r) * XST + jg]      = z0[r];
        xs[(16 + md + r) * XST + jg] = z1[r];
    }
    for (int i = tid; i < 96 * XST / 8; i += 384)
        ((uint4*)wT)[i] = ((const uint4*)wbg2)[i];
    __syncthreads();

    // ---- GEMM2 (K = 96) ----
    f32x4 o0 = {0.f, 0.f, 0.f, 0.f}, o1 = {0.f, 0.f, 0.f, 0.f};
    #pragma unroll
    for (int ks = 0; ks < 3; ++ks) {
        const int k0 = ks * 32 + lk;
        const bf16x8 b  = *(const bf16x8*)&wT[jg * XST + k0];
        const bf16x8 a0 = *(const bf16x8*)&xs[lr * XST + k0];
        const bf16x8 a1 = *(const bf16x8*)&xs[(16 + lr) * XST + k0];
        o0 = __builtin_amdgcn_mfma_f32_16x16x32_bf16(a0, b, o0, 0, 0, 0);
        o1 = __builtin_amdgcn_mfma_f32_16x16x32_bf16(a1, b, o1, 0, 0, 0);
    }

    u16 y0[4], y1[4];
    #pragma unroll
    for (int r = 0; r < 4; ++r) {
        y0[r] = (u16)f2bfb(fmaxf(o0[r] + Bo, 0.0f));
        y1[r] = (u16)f2bfb(fmaxf(o1[r] + Bo, 0.0f));
    }
    #pragma unroll
    for (int r = 0; r < 4; ++r) {
        const int n0 = nbase + md + r;
        if (n0 < Nn) out[(long)n0 * Hh + jg] = y0[r];
        const int n1 = nbase + 16 + md + r;
        if (n1 < Nn) out[(long)n1 * Hh + jg] = y1[r];
    }

    if constexpr (POOL) {
        __syncthreads();                          // GEMM2 xs reads done
        #pragma unroll
        for (int r = 0; r < 4; ++r) {
            xs[(md + r) * XST + jg]      = y0[r];
            xs[(16 + md + r) * XST + jg] = y1[r];
        }
        __syncthreads();
        if (tid < Hh) {
            const int j = tid;
            float acc = 0.0f;
            int bcur = batch[nbase];
            for (int r = 0; r < TILE; ++r) {
                const int node = nbase + r;
                if (node >= Nn) break;
                const int bb = batch[node];
                if (bb != bcur) {
                    atomicAdd(&pooled[(long)bcur * Hh + j], acc);
                    acc = 0.0f;
                    bcur = bb;
                }
                acc += bf2f(xs[r * XST + j]);
            }
            atomicAdd(&pooled[(long)bcur * Hh + j], acc);
        }
    }
}

// ---------------------------------------------------------------------------
// Head: out[b] = dot(pooled[b], head_w[rt[b]]) + head_b[rt[b]]
// ---------------------------------------------------------------------------
__global__ void head_kernel(const float* __restrict__ pooled, const int* __restrict__ rt,
                            const float* __restrict__ hw, const float* __restrict__ hb,
                            float* __restrict__ outv) {
    const int b = blockIdx.x;
    const int lane = threadIdx.x;
    const int t = rt[b];
    const float* pp = pooled + (long)b * Hh;
    const float* wp = hw + (long)t * Hh;
    float s = 0.0f;
    for (int j = lane; j < Hh; j += 64) s += pp[j] * wp[j];
    #pragma unroll
    for (int off = 32; off > 0; off >>= 1) s += __shfl_down(s, off, 64);
    if (lane == 0) outv[b] = s + hb[t];
}

// ---------------------------------------------------------------------------
extern "C" void kernel_launch(void* const* d_in, const int* in_sizes, int n_in,
                              void* d_out, int out_size, void* d_ws, size_t ws_size,
                              hipStream_t stream) {
    const float* x     = (const float*)d_in[0];
    const int*   ei    = (const int*)d_in[1];      // [2, E] flattened int32
    const int*   src   = ei;
    const int*   dst   = ei + Ee;
    const int*   batch = (const int*)d_in[2];
    const int*   rt    = (const int*)d_in[3];

    const float* P[3][8];
    for (int l = 0; l < 3; ++l)
        for (int p = 0; p < 8; ++p)
            P[l][p] = (const float*)d_in[4 + l * 8 + p];
    const float* head_w = (const float*)d_in[28];
    const float* head_b = (const float*)d_in[29];

    // Workspace layout
    const size_t NH = (size_t)Nn * Hh;
    u16*   tA      = (u16*)d_ws;                       // N*H bf16
    u16*   tB      = tA + NH;                          // N*H bf16
    u16*   xb      = tB + NH;                          // N*INF bf16
    u16*   wball   = xb + (size_t)Nn * INF;            // WB_TOT u16 (transposed tables)
    float* pooled  = (float*)(wball + WB_TOT);         // B*H fp32
    int*   rowptr  = (int*)(pooled + (size_t)Bb * Hh); // N+1 ints
    int*   counts  = rowptr + Nn + 1;                  // NBIN*P1B ints
    int*   binbase = counts + NBIN * P1B;              // NBIN ints
    int*   bintot  = binbase + NBIN;                   // NBIN ints
    u16*   csr     = (u16*)(bintot + NBIN);            // E u16
    // binbuf (16.0 MB) overlays tA+tB (19.2 MB) — both dead during CSR build
    u32*   binbuf  = (u32*)tA;
    float* out     = (float*)d_out;

    const dim3 blk256(256), blk384(384), blk512(512);
    const int GRID_L = (Nn + 31) / 32;                 // 1563

    // ----- precompute tables (+ zero bintot/pooled) ; build CSR -----
    x2bf_init_kernel<<<782, blk256, 0, stream>>>(x, xb, bintot, pooled);
    w2bf_kernel<<<(WB_TOT / 2 + 255) / 256, blk256, 0, stream>>>(
        P[0][0], P[0][6], P[1][0], P[1][6], P[2][0], P[2][6], wball);
    p1_bin_kernel<<<P1B, blk256, 0, stream>>>(src, dst, binbuf, counts, bintot);
    p2_binscan_kernel<<<1, blk512, 0, stream>>>(bintot, binbase, rowptr);
    p3_binsort_kernel<<<NBIN, blk256, 0, stream>>>(binbuf, counts, binbase, rowptr, csr);

    // ----- Layer 1: xb -> tA -----
    layer_kernel<INF, false><<<GRID_L, blk384, 0, stream>>>(xb, rowptr, csr,
        wball + 0 * WMAT, wball + 1 * WMAT,
        P[0][1], P[0][2], P[0][3], P[0][4], P[0][5], P[0][7], tA, nullptr, nullptr);

    // ----- Layer 2: tA -> tB -----
    layer_kernel<Hh, false><<<GRID_L, blk384, 0, stream>>>(tA, rowptr, csr,
        wball + 2 * WMAT, wball + 3 * WMAT,
        P[1][1], P[1][2], P[1][3], P[1][4], P[1][5], P[1][7], tB, nullptr, nullptr);

    // ----- Layer 3 (+fused pool): tB -> tA, pooled -----
    layer_kernel<Hh, true><<<GRID_L, blk384, 0, stream>>>(tB, rowptr, csr,
        wball + 4 * WMAT, wball + 5 * WMAT,
        P[2][1], P[2][2], P[2][3], P[2][4], P[2][5], P[2][7], tA, batch, pooled);

    // ----- Head -----
    head_kernel<<<Bb, 64, 0, stream>>>(pooled, rt, head_w, head_b, out);
}